// Round 8
// baseline (187.295 us; speedup 1.0000x reference)
//
#include <hip/hip_runtime.h>
#include <math.h>

typedef __attribute__((ext_vector_type(8))) short s8v;   // 8 x bf16 (4 VGPRs) — MFMA A/B frag
typedef __attribute__((ext_vector_type(4))) float f4v;   // 4 x fp32 — MFMA C/D frag
typedef unsigned short u16;
typedef unsigned int u32;

constexpr int Bsz = 4, NQ = 4096, NC = 1024, NH = 8, DH = 64, DI = 512, DC = 768;

__device__ __forceinline__ u16 f2bf(float f) {
  union { float f; u32 u; } v; v.f = f;
  u32 r = v.u + 0x7fff + ((v.u >> 16) & 1);  // RNE
  return (u16)(r >> 16);
}

__device__ __forceinline__ u32 pack2(float a, float b) {
  union { float f; u32 u; } ua, ub; ua.f = a; ub.f = b;
#if __has_builtin(__builtin_amdgcn_perm)
  return __builtin_amdgcn_perm(ub.u + 0x8000u, ua.u + 0x8000u, 0x07060302u);
#else
  return ((ub.u + 0x8000u) & 0xffff0000u) | ((ua.u + 0x8000u) >> 16);
#endif
}

// single-instruction RNE pack (v_cvt_pk_bf16_f32)
__device__ __forceinline__ u32 cvtpk(float a, float b) {
  u32 r;
  asm("v_cvt_pk_bf16_f32 %0, %1, %2" : "=v"(r) : "v"(a), "v"(b));
  return r;
}

#if __has_builtin(__builtin_amdgcn_exp2f)
#define EXP2(x) __builtin_amdgcn_exp2f(x)
#else
#define EXP2(x) exp2f(x)
#endif

// async global->LDS, 16B per lane (m97 pattern)
__device__ __forceinline__ void g2l16(const void* g, void* l) {
  __builtin_amdgcn_global_load_lds((const __attribute__((address_space(1))) u32*)g,
                                   (__attribute__((address_space(3))) u32*)l, 16, 0, 0);
}

// ---------------- prep: casts + all weight transposes in one launch (R0-verified) --------
__global__ __launch_bounds__(256) void prep(const float* __restrict__ x, const float* __restrict__ ctx,
                                            const float* __restrict__ Wq, const float* __restrict__ Wk,
                                            const float* __restrict__ Wv, const float* __restrict__ Wo,
                                            u16* __restrict__ xb, u16* __restrict__ cb,
                                            u16* __restrict__ wqT, u16* __restrict__ wkvT,
                                            u16* __restrict__ woT) {
  int bx = blockIdx.x;
  if (bx < 11264) {                       // cast path: x then ctx, float4-vectorized
    const int NX4 = Bsz * NQ * DI / 4;    // 2097152
    const int NC4 = Bsz * NC * DC / 4;    // 786432
    int i = bx * 256 + threadIdx.x;
    float4 v; u16* dst; int j;
    if (i < NX4) { v = ((const float4*)x)[i]; dst = xb; j = i; }
    else { j = i - NX4; if (j >= NC4) return; v = ((const float4*)ctx)[j]; dst = cb; }
    ushort4 o; o.x = f2bf(v.x); o.y = f2bf(v.y); o.z = f2bf(v.z); o.w = f2bf(v.w);
    ((ushort4*)dst)[j] = o;
    return;
  }
  int idx = bx - 11264;                   // [0,384): weight transpose W[K][N] -> W^T[N][K] bf16
  int z = idx / 96, rem = idx % 96, kx = rem % 12, ny = rem / 12;
  const float* src; u16* dst; int K; const int N = 512;
  if (z == 0)      { src = Wq; dst = wqT;              K = 512; }
  else if (z == 1) { src = Wk; dst = wkvT;             K = 768; }
  else if (z == 2) { src = Wv; dst = wkvT + 512 * 768; K = 768; }
  else             { src = Wo; dst = woT;              K = 512; }
  int k0 = kx * 64, n0 = ny * 64;
  if (k0 >= K) return;
  __shared__ u16 t[64][65];
  int tid = threadIdx.x, jr = tid & 63, ir = tid >> 6;
  for (int it = 0; it < 16; ++it) { int i = it * 4 + ir; t[i][jr] = f2bf(src[(size_t)(k0 + i) * N + n0 + jr]); }
  __syncthreads();
  for (int it = 0; it < 16; ++it) { int i = it * 4 + ir; dst[(size_t)(n0 + i) * K + k0 + jr] = t[jr][i]; }
}

// ---------------- 8-phase GEMM body: 128x256 tile, BK=64, 512 threads, 8 waves ----------------
// (R7-verified: T3+T4 8-phase counted-vmcnt schedule; 3 K-tile LDS buffers; vmcnt(6) at
// phases 4/8 only; XOR-chunk swizzle both-sides involution; setprio around MFMA clusters.)
template <int MODE>
__device__ __forceinline__ void gemm8p(const u16* __restrict__ A, const u16* __restrict__ Bt,
                                       void* __restrict__ C0, void* __restrict__ C1,
                                       const float* __restrict__ bias, int N, int K,
                                       float oscale, int nbx, int mby,
                                       u16* Ash, u16* Bsh) {   // Ash: 3*8192, Bsh: 3*16384 (u16)
  int tid = threadIdx.x;                  // 0..511
  int lane = tid & 63, quad = lane >> 4, l16 = lane & 15, wave = tid >> 6;
  int wm = (wave >> 2) * 64, wn = (wave & 3) * 64;   // 2M x 4N wave grid; 64x64 per wave
  int mb = mby * 128, nb = nbx * 256;
  int x7 = l16 & 7;
  f4v acc[4][4];
  #pragma unroll
  for (int i = 0; i < 4; i++)
    #pragma unroll
    for (int j = 0; j < 4; j++) acc[i][j] = (f4v){0.f, 0.f, 0.f, 0.f};

  int srow = tid >> 3;
  int sc = ((tid & 7) ^ (srow & 7)) * 8;
  const u16* Ap0 = A  + (size_t)(mb + srow) * K + sc;
  const u16* Bq0 = Bt + (size_t)(nb + srow) * K + sc;
  int lin = tid * 8;

#define SA(ts, dst) do { const u16* s_ = Ap0 + (size_t)(ts) * 64; \
    g2l16(s_, (dst) + lin); g2l16(s_ + (size_t)64 * K, (dst) + 4096 + lin); } while (0)
#define SB0(ts, dst) do { const u16* s_ = Bq0 + (size_t)(ts) * 64; \
    g2l16(s_, (dst) + lin); g2l16(s_ + (size_t)64 * K, (dst) + 4096 + lin); } while (0)
#define SB1(ts, dst) do { const u16* s_ = Bq0 + (size_t)(ts) * 64 + (size_t)128 * K; \
    g2l16(s_, (dst) + 8192 + lin); g2l16(s_ + (size_t)64 * K, (dst) + 12288 + lin); } while (0)

  int ak0 = ((0 + quad) ^ x7) * 8;
  int ak1 = ((4 + quad) ^ x7) * 8;

  s8v bfr[4];
#define PHASE(ABUF, BBUF, AKK, IP, LOADB, WAITN, ...) do { \
    if (LOADB) { \
      bfr[0] = *(const s8v*)((BBUF) + (wn +  0 + l16) * 64 + (AKK)); \
      bfr[1] = *(const s8v*)((BBUF) + (wn + 16 + l16) * 64 + (AKK)); \
      bfr[2] = *(const s8v*)((BBUF) + (wn + 32 + l16) * 64 + (AKK)); \
      bfr[3] = *(const s8v*)((BBUF) + (wn + 48 + l16) * 64 + (AKK)); \
    } \
    s8v af0 = *(const s8v*)((ABUF) + (wm + (IP) * 32 + l16) * 64 + (AKK)); \
    s8v af1 = *(const s8v*)((ABUF) + (wm + (IP) * 32 + 16 + l16) * 64 + (AKK)); \
    __VA_ARGS__; \
    { int wv_ = (WAITN); \
      if (wv_ == 6) asm volatile("s_waitcnt vmcnt(6)" ::: "memory"); \
      else if (wv_ == 0) asm volatile("s_waitcnt vmcnt(0)" ::: "memory"); } \
    asm volatile("" ::: "memory"); __builtin_amdgcn_s_barrier(); asm volatile("" ::: "memory"); \
    __builtin_amdgcn_s_setprio(1); \
    _Pragma("unroll") \
    for (int j = 0; j < 4; j++) { \
      acc[(IP)*2][j]   = __builtin_amdgcn_mfma_f32_16x16x32_bf16(af0, bfr[j], acc[(IP)*2][j],   0, 0, 0); \
      acc[(IP)*2+1][j] = __builtin_amdgcn_mfma_f32_16x16x32_bf16(af1, bfr[j], acc[(IP)*2+1][j], 0, 0, 0); \
    } \
    __builtin_amdgcn_s_setprio(0); \
    asm volatile("" ::: "memory"); __builtin_amdgcn_s_barrier(); asm volatile("" ::: "memory"); \
  } while (0)

  u16 *A0 = Ash, *A1 = Ash + 8192, *A2 = Ash + 16384;
  u16 *B0 = Bsh, *B1 = Bsh + 16384, *B2 = Bsh + 32768;

  SA(0, A0); SB0(0, B0); SB1(0, B0);
  SA(1, A1); SB0(1, B1); SB1(1, B1);
  asm volatile("s_waitcnt vmcnt(6)" ::: "memory");
  __builtin_amdgcn_s_barrier();
  asm volatile("" ::: "memory");

  int nkt = K >> 6;
  for (int t2 = 0; t2 < nkt; t2 += 2) {
    bool more = (t2 + 2 < nkt);
    PHASE(A0, B0, ak0, 0, true,  -1, if (more) SA(t2 + 2, A2));
    PHASE(A0, B0, ak0, 1, false, -1, if (more) SB0(t2 + 2, B2));
    PHASE(A0, B0, ak1, 0, true,  -1, if (more) SB1(t2 + 2, B2));
    PHASE(A0, B0, ak1, 1, false, (more ? 6 : 0), );
    PHASE(A1, B1, ak0, 0, true,  -1, if (more) SA(t2 + 3, A0));
    PHASE(A1, B1, ak0, 1, false, -1, if (more) SB0(t2 + 3, B0));
    PHASE(A1, B1, ak1, 0, true,  -1, if (more) SB1(t2 + 3, B0));
    PHASE(A1, B1, ak1, 1, false, (more ? 6 : -1), );
    u16* tA = A0; A0 = A2; A2 = A1; A1 = tA;
    u16* tB = B0; B0 = B2; B2 = B1; B1 = tB;
  }
#undef PHASE
#undef SA
#undef SB0
#undef SB1

  #pragma unroll
  for (int i = 0; i < 4; i++) {
    int rbase = mb + wm + i * 16 + quad * 4;
    #pragma unroll
    for (int j = 0; j < 4; j++) {
      int col = nb + wn + j * 16 + l16;
      if (MODE == 0) {
        u16* Cb = (u16*)C0;
        #pragma unroll
        for (int r = 0; r < 4; r++) Cb[(size_t)(rbase + r) * N + col] = f2bf(acc[i][j][r] * oscale);
      } else if (MODE == 1) {
        float* Cf = (float*)C0;
        #pragma unroll
        for (int r = 0; r < 4; r++) Cf[(size_t)(rbase + r) * N + col] = acc[i][j][r] + bias[col];
      } else {
        if (col < 512) {                  // K projection -> Kb [b*NC+t][512]
          u16* Kb = (u16*)C0;
          #pragma unroll
          for (int r = 0; r < 4; r++) Kb[(size_t)(rbase + r) * 512 + col] = f2bf(acc[i][j][r]);
        } else {                          // V projection -> Vt, transposed + key-permuted
          u16* Vt = (u16*)C1;
          int hd = col - 512, h = hd >> 6, d = hd & 63;
          int bb = rbase >> 10, tl = rbase & 1023;
          int tbase = tl & ~63, a0 = tl & 63;
          int pb = (a0 & 32) + ((a0 & 15) >> 2) * 8 + (((a0 >> 4) & 1) << 2);
          uint2 ov;
          ov.x = pack2(acc[i][j][0], acc[i][j][1]);
          ov.y = pack2(acc[i][j][2], acc[i][j][3]);
          *(uint2*)(Vt + ((size_t)(bb * NH + h) * DH + d) * NC + tbase + pb) = ov;
        }
      }
    }
  }
}

// ---------------- fused QKV projection (bf16 A from prep), XCD-chunked, KV first ----------------
__global__ __launch_bounds__(512, 2) void proj_all(const u16* __restrict__ xb, const u16* __restrict__ cb,
                                                   const u16* __restrict__ wqT, const u16* __restrict__ wkvT,
                                                   u16* __restrict__ Qb, u16* __restrict__ Kb,
                                                   u16* __restrict__ Vtb, float qscale) {
  __shared__ alignas(16) u16 Ash[3 * 8192];    // 48 KB
  __shared__ alignas(16) u16 Bsh[3 * 16384];   // 96 KB
  int bx = blockIdx.x;
  if (bx < 128) {  // KV: M=4096, N=1024, K=768 -> 32x4 blocks of 128x256
    int bi = (bx & 7) * 16 + (bx >> 3);        // XCD-chunked [0,128)
    gemm8p<2>(cb, wkvT, Kb, Vtb, nullptr, 1024, 768, 1.0f, bi & 3, bi >> 2, Ash, Bsh);
  } else {         // Q: M=16384, N=512, K=512 -> 128x2 blocks
    int bq = bx - 128;
    int bi = (bq & 7) * 32 + (bq >> 3);        // [0,256)
    gemm8p<0>(xb, wqT, Qb, nullptr, nullptr, 512, 512, qscale, bi & 1, bi >> 1, Ash, Bsh);
  }
}

// ---------------- output projection (fp32 out + bias) ----------------
__global__ __launch_bounds__(512, 2) void outproj(const u16* __restrict__ Ob, const u16* __restrict__ woT,
                                                  float* __restrict__ out, const float* __restrict__ bo) {
  __shared__ alignas(16) u16 Ash[3 * 8192];
  __shared__ alignas(16) u16 Bsh[3 * 16384];
  int bx = blockIdx.x;
  int bi = (bx & 7) * 32 + (bx >> 3);          // [0,256)
  gemm8p<1>(Ob, woT, out, nullptr, bo, 512, 512, 1.0f, bi & 1, bi >> 1, Ash, Bsh);
}

// ---------------- flash cross-attention: 64 q/wave, 2-wave blocks, 64-key tiles ----------------
// R8: R7 profile put attn LDS pipe at ~3070 cy/kt/CU vs MFMA 2790 (MFMA:ds_read only 2.25).
// Doubling q per wave (32->64) keeps 16 ds_read_b128/wave/kt but doubles MFMA to 72 ->
// per-CU LDS demand halves; MFMA total unchanged; VALU per-FLOP unchanged.
// 128-thread blocks (2 waves x 64 q), grid (32,8,4) = 4 independent blocks/CU (128KB LDS),
// lb(128,2) -> 256-VGPR cap (est ~210 live). All n-loops are compile-time (n=0..3).
__global__ __launch_bounds__(128, 2) void attn(const u16* __restrict__ Q, const u16* __restrict__ Kb,
                                               const u16* __restrict__ Vt, u16* __restrict__ O) {
  __shared__ alignas(16) u16 Kl[2][64][64];   // 16 KB
  __shared__ alignas(16) u16 Vl[2][64][64];   // 16 KB
  int qt = blockIdx.x, h = blockIdx.y, b = blockIdx.z;
  int tid = threadIdx.x, wave = tid >> 6, lane = tid & 63, quad = lane >> 4, l16 = lane & 15;
  int q0 = qt * 128 + wave * 64;
  int x7 = l16 & 7;

  // staging (128 threads): thread -> row tid>>3 in [0,16), source chunk (tid&7)^(row&7);
  // 4 calls per tile at row offsets 0,16,32,48 (row&7 invariant -> same involution as read).
  int kr = tid >> 3, kc = (tid & 7) ^ (kr & 7);
  const u16* kg = Kb + ((size_t)b * NC + kr) * 512 + h * DH + kc * 8;
  const u16* vg = Vt + ((size_t)(b * NH + h) * DH + kr) * NC + kc * 8;

#define ASTAGE(kt, buf) do { \
    const u16* kg_ = kg + (size_t)(kt) * 64 * 512; \
    const u16* vg_ = vg + (kt) * 64; \
    u16* kl_ = (u16*)Kl + (buf) * 4096; u16* vl_ = (u16*)Vl + (buf) * 4096; \
    g2l16(kg_,            kl_ + tid * 8); \
    g2l16(kg_ + 16 * 512, kl_ + (tid + 128) * 8); \
    g2l16(kg_ + 32 * 512, kl_ + (tid + 256) * 8); \
    g2l16(kg_ + 48 * 512, kl_ + (tid + 384) * 8); \
    g2l16(vg_,            vl_ + tid * 8); \
    g2l16(vg_ + 16 * NC,  vl_ + (tid + 128) * 8); \
    g2l16(vg_ + 32 * NC,  vl_ + (tid + 256) * 8); \
    g2l16(vg_ + 48 * NC,  vl_ + (tid + 384) * 8); } while (0)

  // Q B-frags for 4 n-subtiles x 2 dh-chunks, in regs for the whole kernel (32 VGPR)
  s8v aq[4][2];
  {
    const u16* Qp = Q + ((size_t)b * NQ + q0 + l16) * DI + h * DH + quad * 8;
    #pragma unroll
    for (int n = 0; n < 4; n++) {
      aq[n][0] = *(const s8v*)(Qp + (size_t)n * 16 * DI);
      aq[n][1] = *(const s8v*)(Qp + (size_t)n * 16 * DI + 32);
    }
  }
  s8v vones;
  #pragma unroll
  for (int i = 0; i < 8; i++) vones[i] = (short)0x3F80;

  f4v oacc[4][4];
  f4v lacc[4];
  #pragma unroll
  for (int d = 0; d < 4; d++)
    #pragma unroll
    for (int n = 0; n < 4; n++) oacc[d][n] = (f4v){0.f, 0.f, 0.f, 0.f};
  #pragma unroll
  for (int n = 0; n < 4; n++) lacc[n] = (f4v){0.f, 0.f, 0.f, 0.f};

  ASTAGE(0, 0);
  for (int kt = 0; kt < NC / 64; ++kt) {
    int buf = kt & 1;
    __syncthreads();
    if (kt + 1 < NC / 64) ASTAGE(kt + 1, buf ^ 1);
    const u16* kb = (const u16*)Kl + buf * 4096;
    const u16* vb = (const u16*)Vl + buf * 4096;

    // ---- QK^T for both 32-key chunks (8 ds_read_b128 + 32 MFMA) ----
    f4v S0[2][4], S1[2][4];
    #pragma unroll
    for (int mi = 0; mi < 2; mi++)
      #pragma unroll
      for (int n = 0; n < 4; n++) { S0[mi][n] = (f4v){0.f,0.f,0.f,0.f}; S1[mi][n] = (f4v){0.f,0.f,0.f,0.f}; }
    __builtin_amdgcn_s_setprio(1);
    #pragma unroll
    for (int cd = 0; cd < 2; cd++) {
      int ch = ((4 * cd + quad) ^ x7) * 8;
      s8v k00 = *(const s8v*)(kb + (l16     ) * 64 + ch);
      s8v k01 = *(const s8v*)(kb + (l16 + 16) * 64 + ch);
      #pragma unroll
      for (int n = 0; n < 4; n++) {
        S0[0][n] = __builtin_amdgcn_mfma_f32_16x16x32_bf16(k00, aq[n][cd], S0[0][n], 0, 0, 0);
        S0[1][n] = __builtin_amdgcn_mfma_f32_16x16x32_bf16(k01, aq[n][cd], S0[1][n], 0, 0, 0);
      }
      s8v k10 = *(const s8v*)(kb + (l16 + 32) * 64 + ch);
      s8v k11 = *(const s8v*)(kb + (l16 + 48) * 64 + ch);
      #pragma unroll
      for (int n = 0; n < 4; n++) {
        S1[0][n] = __builtin_amdgcn_mfma_f32_16x16x32_bf16(k10, aq[n][cd], S1[0][n], 0, 0, 0);
        S1[1][n] = __builtin_amdgcn_mfma_f32_16x16x32_bf16(k11, aq[n][cd], S1[1][n], 0, 0, 0);
      }
    }
    __builtin_amdgcn_s_setprio(0);

    // ---- softmax chunk 0 ----
    s8v pf0[4];
    #pragma unroll
    for (int n = 0; n < 4; n++) {
      float p00 = EXP2(S0[0][n][0]), p01 = EXP2(S0[0][n][1]), p02 = EXP2(S0[0][n][2]), p03 = EXP2(S0[0][n][3]);
      float p10 = EXP2(S0[1][n][0]), p11 = EXP2(S0[1][n][1]), p12 = EXP2(S0[1][n][2]), p13 = EXP2(S0[1][n][3]);
      union { u32 d[4]; s8v v; } u;
      u.d[0] = cvtpk(p00, p01); u.d[1] = cvtpk(p02, p03);
      u.d[2] = cvtpk(p10, p11); u.d[3] = cvtpk(p12, p13);
      pf0[n] = u.v;
    }
    // ---- PV chunk 0 + denominator ----
    __builtin_amdgcn_s_setprio(1);
    #pragma unroll
    for (int n = 0; n < 4; n++)
      lacc[n] = __builtin_amdgcn_mfma_f32_16x16x32_bf16(vones, pf0[n], lacc[n], 0, 0, 0);
    #pragma unroll
    for (int d = 0; d < 4; d++) {
      int ch = (quad ^ x7) * 8;
      s8v vf = *(const s8v*)(vb + (d * 16 + l16) * 64 + ch);
      #pragma unroll
      for (int n = 0; n < 4; n++)
        oacc[d][n] = __builtin_amdgcn_mfma_f32_16x16x32_bf16(vf, pf0[n], oacc[d][n], 0, 0, 0);
    }
    __builtin_amdgcn_s_setprio(0);

    // ---- softmax chunk 1 (overlaps PV c0) ----
    s8v pf1[4];
    #pragma unroll
    for (int n = 0; n < 4; n++) {
      float p00 = EXP2(S1[0][n][0]), p01 = EXP2(S1[0][n][1]), p02 = EXP2(S1[0][n][2]), p03 = EXP2(S1[0][n][3]);
      float p10 = EXP2(S1[1][n][0]), p11 = EXP2(S1[1][n][1]), p12 = EXP2(S1[1][n][2]), p13 = EXP2(S1[1][n][3]);
      union { u32 d[4]; s8v v; } u;
      u.d[0] = cvtpk(p00, p01); u.d[1] = cvtpk(p02, p03);
      u.d[2] = cvtpk(p10, p11); u.d[3] = cvtpk(p12, p13);
      pf1[n] = u.v;
    }
    // ---- PV chunk 1 + denominator ----
    __builtin_amdgcn_s_setprio(1);
    #pragma unroll
    for (int n = 0; n < 4; n++)
      lacc[n] = __builtin_amdgcn_mfma_f32_16x16x32_bf16(vones, pf1[n], lacc[n], 0, 0, 0);
    #pragma unroll
    for (int d = 0; d < 4; d++) {
      int ch = ((4 + quad) ^ x7) * 8;
      s8v vf = *(const s8v*)(vb + (d * 16 + l16) * 64 + ch);
      #pragma unroll
      for (int n = 0; n < 4; n++)
        oacc[d][n] = __builtin_amdgcn_mfma_f32_16x16x32_bf16(vf, pf1[n], oacc[d][n], 0, 0, 0);
    }
    __builtin_amdgcn_s_setprio(0);
  }
#undef ASTAGE

  float inv[4];
  #pragma unroll
  for (int n = 0; n < 4; n++) inv[n] = 1.0f / lacc[n][0];

  #pragma unroll
  for (int d = 0; d < 4; d++)
    #pragma unroll
    for (int n = 0; n < 4; n++) {
      int q = q0 + n * 16 + l16;
      uint2 ov;
      ov.x = cvtpk(oacc[d][n][0] * inv[n], oacc[d][n][1] * inv[n]);
      ov.y = cvtpk(oacc[d][n][2] * inv[n], oacc[d][n][3] * inv[n]);
      *(uint2*)(O + ((size_t)b * NQ + q) * DI + h * DH + d * 16 + quad * 4) = ov;
    }
}

extern "C" void kernel_launch(void* const* d_in, const int* in_sizes, int n_in,
                              void* d_out, int out_size, void* d_ws, size_t ws_size,
                              hipStream_t stream) {
  const float* x   = (const float*)d_in[0];
  const float* ctx = (const float*)d_in[1];
  const float* Wq  = (const float*)d_in[2];
  const float* Wk  = (const float*)d_in[3];
  const float* Wv  = (const float*)d_in[4];
  const float* Wo  = (const float*)d_in[5];
  const float* bo  = (const float*)d_in[6];
  float* out = (float*)d_out;

  u16* w    = (u16*)d_ws;                // workspace layout (bf16 elems)
  u16* xb   = w;                         // 8388608
  u16* cb   = xb   + 8388608;            // 3145728
  u16* wqT  = cb   + 3145728;            // 262144
  u16* wkvT = wqT  + 262144;             // 786432 (Wk^T rows 0-511, Wv^T rows 512-1023)
  u16* woT  = wkvT + 786432;             // 262144
  u16* Qb   = woT  + 262144;             // 8388608 (pre-scaled by 0.125*log2e)
  u16* Kbuf = Qb   + 8388608;            // 2097152 ([b*1024+t][512])
  u16* Vtb  = Kbuf + 2097152;            // 2097152 (key-permuted V^T)
  u16* Ob   = Vtb  + 2097152;            // 8388608

  const float qscale = 0.125f * 1.44269504f;  // softmax scale + log2(e) folded into Q

  prep<<<11648, 256, 0, stream>>>(x, ctx, Wq, Wk, Wv, Wo, xb, cb, wqT, wkvT, woT);
  proj_all<<<384, 512, 0, stream>>>(xb, cb, wqT, wkvT, Qb, Kbuf, Vtb, qscale);
  attn<<<dim3(32, 8, 4), 128, 0, stream>>>(Qb, Kbuf, Vtb, Ob);
  outproj<<<256, 512, 0, stream>>>(Ob, woT, out, bo);
}

// Round 9
// 179.821 us; speedup vs baseline: 1.0416x; 1.0416x over previous
//
#include <hip/hip_runtime.h>
#include <math.h>

typedef __attribute__((ext_vector_type(8))) short s8v;   // 8 x bf16 (4 VGPRs) — MFMA A/B frag
typedef __attribute__((ext_vector_type(4))) float f4v;   // 4 x fp32 — MFMA C/D frag
typedef unsigned short u16;
typedef unsigned int u32;

constexpr int Bsz = 4, NQ = 4096, NC = 1024, NH = 8, DH = 64, DI = 512, DC = 768;

__device__ __forceinline__ u16 f2bf(float f) {
  union { float f; u32 u; } v; v.f = f;
  u32 r = v.u + 0x7fff + ((v.u >> 16) & 1);  // RNE
  return (u16)(r >> 16);
}

__device__ __forceinline__ u32 pack2(float a, float b) {
  union { float f; u32 u; } ua, ub; ua.f = a; ub.f = b;
#if __has_builtin(__builtin_amdgcn_perm)
  return __builtin_amdgcn_perm(ub.u + 0x8000u, ua.u + 0x8000u, 0x07060302u);
#else
  return ((ub.u + 0x8000u) & 0xffff0000u) | ((ua.u + 0x8000u) >> 16);
#endif
}

// single-instruction RNE pack (v_cvt_pk_bf16_f32)
__device__ __forceinline__ u32 cvtpk(float a, float b) {
  u32 r;
  asm("v_cvt_pk_bf16_f32 %0, %1, %2" : "=v"(r) : "v"(a), "v"(b));
  return r;
}

#if __has_builtin(__builtin_amdgcn_exp2f)
#define EXP2(x) __builtin_amdgcn_exp2f(x)
#else
#define EXP2(x) exp2f(x)
#endif

// async global->LDS, 16B per lane (m97 pattern)
__device__ __forceinline__ void g2l16(const void* g, void* l) {
  __builtin_amdgcn_global_load_lds((const __attribute__((address_space(1))) u32*)g,
                                   (__attribute__((address_space(3))) u32*)l, 16, 0, 0);
}

// ---------------- prep: casts + all weight transposes in one launch (R0-verified) --------
__global__ __launch_bounds__(256) void prep(const float* __restrict__ x, const float* __restrict__ ctx,
                                            const float* __restrict__ Wq, const float* __restrict__ Wk,
                                            const float* __restrict__ Wv, const float* __restrict__ Wo,
                                            u16* __restrict__ xb, u16* __restrict__ cb,
                                            u16* __restrict__ wqT, u16* __restrict__ wkvT,
                                            u16* __restrict__ woT) {
  int bx = blockIdx.x;
  if (bx < 11264) {                       // cast path: x then ctx, float4-vectorized
    const int NX4 = Bsz * NQ * DI / 4;    // 2097152
    const int NC4 = Bsz * NC * DC / 4;    // 786432
    int i = bx * 256 + threadIdx.x;
    float4 v; u16* dst; int j;
    if (i < NX4) { v = ((const float4*)x)[i]; dst = xb; j = i; }
    else { j = i - NX4; if (j >= NC4) return; v = ((const float4*)ctx)[j]; dst = cb; }
    ushort4 o; o.x = f2bf(v.x); o.y = f2bf(v.y); o.z = f2bf(v.z); o.w = f2bf(v.w);
    ((ushort4*)dst)[j] = o;
    return;
  }
  int idx = bx - 11264;                   // [0,384): weight transpose W[K][N] -> W^T[N][K] bf16
  int z = idx / 96, rem = idx % 96, kx = rem % 12, ny = rem / 12;
  const float* src; u16* dst; int K; const int N = 512;
  if (z == 0)      { src = Wq; dst = wqT;              K = 512; }
  else if (z == 1) { src = Wk; dst = wkvT;             K = 768; }
  else if (z == 2) { src = Wv; dst = wkvT + 512 * 768; K = 768; }
  else             { src = Wo; dst = woT;              K = 512; }
  int k0 = kx * 64, n0 = ny * 64;
  if (k0 >= K) return;
  __shared__ u16 t[64][65];
  int tid = threadIdx.x, jr = tid & 63, ir = tid >> 6;
  for (int it = 0; it < 16; ++it) { int i = it * 4 + ir; t[i][jr] = f2bf(src[(size_t)(k0 + i) * N + n0 + jr]); }
  __syncthreads();
  for (int it = 0; it < 16; ++it) { int i = it * 4 + ir; dst[(size_t)(n0 + i) * K + k0 + jr] = t[jr][i]; }
}

// ---------------- 8-phase GEMM body: 128x256 tile, BK=64, 512 threads, 8 waves ----------------
// (R7-verified: T3+T4 8-phase counted-vmcnt schedule; 3 K-tile LDS buffers; vmcnt(6) at
// phases 4/8 only; XOR-chunk swizzle both-sides involution; setprio around MFMA clusters.)
template <int MODE>
__device__ __forceinline__ void gemm8p(const u16* __restrict__ A, const u16* __restrict__ Bt,
                                       void* __restrict__ C0, void* __restrict__ C1,
                                       const float* __restrict__ bias, int N, int K,
                                       float oscale, int nbx, int mby,
                                       u16* Ash, u16* Bsh) {   // Ash: 3*8192, Bsh: 3*16384 (u16)
  int tid = threadIdx.x;                  // 0..511
  int lane = tid & 63, quad = lane >> 4, l16 = lane & 15, wave = tid >> 6;
  int wm = (wave >> 2) * 64, wn = (wave & 3) * 64;   // 2M x 4N wave grid; 64x64 per wave
  int mb = mby * 128, nb = nbx * 256;
  int x7 = l16 & 7;
  f4v acc[4][4];
  #pragma unroll
  for (int i = 0; i < 4; i++)
    #pragma unroll
    for (int j = 0; j < 4; j++) acc[i][j] = (f4v){0.f, 0.f, 0.f, 0.f};

  int srow = tid >> 3;
  int sc = ((tid & 7) ^ (srow & 7)) * 8;
  const u16* Ap0 = A  + (size_t)(mb + srow) * K + sc;
  const u16* Bq0 = Bt + (size_t)(nb + srow) * K + sc;
  int lin = tid * 8;

#define SA(ts, dst) do { const u16* s_ = Ap0 + (size_t)(ts) * 64; \
    g2l16(s_, (dst) + lin); g2l16(s_ + (size_t)64 * K, (dst) + 4096 + lin); } while (0)
#define SB0(ts, dst) do { const u16* s_ = Bq0 + (size_t)(ts) * 64; \
    g2l16(s_, (dst) + lin); g2l16(s_ + (size_t)64 * K, (dst) + 4096 + lin); } while (0)
#define SB1(ts, dst) do { const u16* s_ = Bq0 + (size_t)(ts) * 64 + (size_t)128 * K; \
    g2l16(s_, (dst) + 8192 + lin); g2l16(s_ + (size_t)64 * K, (dst) + 12288 + lin); } while (0)

  int ak0 = ((0 + quad) ^ x7) * 8;
  int ak1 = ((4 + quad) ^ x7) * 8;

  s8v bfr[4];
#define PHASE(ABUF, BBUF, AKK, IP, LOADB, WAITN, ...) do { \
    if (LOADB) { \
      bfr[0] = *(const s8v*)((BBUF) + (wn +  0 + l16) * 64 + (AKK)); \
      bfr[1] = *(const s8v*)((BBUF) + (wn + 16 + l16) * 64 + (AKK)); \
      bfr[2] = *(const s8v*)((BBUF) + (wn + 32 + l16) * 64 + (AKK)); \
      bfr[3] = *(const s8v*)((BBUF) + (wn + 48 + l16) * 64 + (AKK)); \
    } \
    s8v af0 = *(const s8v*)((ABUF) + (wm + (IP) * 32 + l16) * 64 + (AKK)); \
    s8v af1 = *(const s8v*)((ABUF) + (wm + (IP) * 32 + 16 + l16) * 64 + (AKK)); \
    __VA_ARGS__; \
    { int wv_ = (WAITN); \
      if (wv_ == 6) asm volatile("s_waitcnt vmcnt(6)" ::: "memory"); \
      else if (wv_ == 0) asm volatile("s_waitcnt vmcnt(0)" ::: "memory"); } \
    asm volatile("" ::: "memory"); __builtin_amdgcn_s_barrier(); asm volatile("" ::: "memory"); \
    __builtin_amdgcn_s_setprio(1); \
    _Pragma("unroll") \
    for (int j = 0; j < 4; j++) { \
      acc[(IP)*2][j]   = __builtin_amdgcn_mfma_f32_16x16x32_bf16(af0, bfr[j], acc[(IP)*2][j],   0, 0, 0); \
      acc[(IP)*2+1][j] = __builtin_amdgcn_mfma_f32_16x16x32_bf16(af1, bfr[j], acc[(IP)*2+1][j], 0, 0, 0); \
    } \
    __builtin_amdgcn_s_setprio(0); \
    asm volatile("" ::: "memory"); __builtin_amdgcn_s_barrier(); asm volatile("" ::: "memory"); \
  } while (0)

  u16 *A0 = Ash, *A1 = Ash + 8192, *A2 = Ash + 16384;
  u16 *B0 = Bsh, *B1 = Bsh + 16384, *B2 = Bsh + 32768;

  SA(0, A0); SB0(0, B0); SB1(0, B0);
  SA(1, A1); SB0(1, B1); SB1(1, B1);
  asm volatile("s_waitcnt vmcnt(6)" ::: "memory");
  __builtin_amdgcn_s_barrier();
  asm volatile("" ::: "memory");

  int nkt = K >> 6;
  for (int t2 = 0; t2 < nkt; t2 += 2) {
    bool more = (t2 + 2 < nkt);
    PHASE(A0, B0, ak0, 0, true,  -1, if (more) SA(t2 + 2, A2));
    PHASE(A0, B0, ak0, 1, false, -1, if (more) SB0(t2 + 2, B2));
    PHASE(A0, B0, ak1, 0, true,  -1, if (more) SB1(t2 + 2, B2));
    PHASE(A0, B0, ak1, 1, false, (more ? 6 : 0), );
    PHASE(A1, B1, ak0, 0, true,  -1, if (more) SA(t2 + 3, A0));
    PHASE(A1, B1, ak0, 1, false, -1, if (more) SB0(t2 + 3, B0));
    PHASE(A1, B1, ak1, 0, true,  -1, if (more) SB1(t2 + 3, B0));
    PHASE(A1, B1, ak1, 1, false, (more ? 6 : -1), );
    u16* tA = A0; A0 = A2; A2 = A1; A1 = tA;
    u16* tB = B0; B0 = B2; B2 = B1; B1 = tB;
  }
#undef PHASE
#undef SA
#undef SB0
#undef SB1

  #pragma unroll
  for (int i = 0; i < 4; i++) {
    int rbase = mb + wm + i * 16 + quad * 4;
    #pragma unroll
    for (int j = 0; j < 4; j++) {
      int col = nb + wn + j * 16 + l16;
      if (MODE == 0) {
        u16* Cb = (u16*)C0;
        #pragma unroll
        for (int r = 0; r < 4; r++) Cb[(size_t)(rbase + r) * N + col] = f2bf(acc[i][j][r] * oscale);
      } else if (MODE == 1) {
        float* Cf = (float*)C0;
        #pragma unroll
        for (int r = 0; r < 4; r++) Cf[(size_t)(rbase + r) * N + col] = acc[i][j][r] + bias[col];
      } else {
        if (col < 512) {                  // K projection -> Kb [b*NC+t][512]
          u16* Kb = (u16*)C0;
          #pragma unroll
          for (int r = 0; r < 4; r++) Kb[(size_t)(rbase + r) * 512 + col] = f2bf(acc[i][j][r]);
        } else {                          // V projection -> Vt, transposed + key-permuted
          u16* Vt = (u16*)C1;
          int hd = col - 512, h = hd >> 6, d = hd & 63;
          int bb = rbase >> 10, tl = rbase & 1023;
          int tbase = tl & ~63, a0 = tl & 63;
          int pb = (a0 & 32) + ((a0 & 15) >> 2) * 8 + (((a0 >> 4) & 1) << 2);
          uint2 ov;
          ov.x = pack2(acc[i][j][0], acc[i][j][1]);
          ov.y = pack2(acc[i][j][2], acc[i][j][3]);
          *(uint2*)(Vt + ((size_t)(bb * NH + h) * DH + d) * NC + tbase + pb) = ov;
        }
      }
    }
  }
}

// ---------------- fused QKV projection (bf16 A from prep), XCD-chunked, KV first ----------------
__global__ __launch_bounds__(512, 2) void proj_all(const u16* __restrict__ xb, const u16* __restrict__ cb,
                                                   const u16* __restrict__ wqT, const u16* __restrict__ wkvT,
                                                   u16* __restrict__ Qb, u16* __restrict__ Kb,
                                                   u16* __restrict__ Vtb, float qscale) {
  __shared__ alignas(16) u16 Ash[3 * 8192];    // 48 KB
  __shared__ alignas(16) u16 Bsh[3 * 16384];   // 96 KB
  int bx = blockIdx.x;
  if (bx < 128) {  // KV: M=4096, N=1024, K=768 -> 32x4 blocks of 128x256
    int bi = (bx & 7) * 16 + (bx >> 3);        // XCD-chunked [0,128)
    gemm8p<2>(cb, wkvT, Kb, Vtb, nullptr, 1024, 768, 1.0f, bi & 3, bi >> 2, Ash, Bsh);
  } else {         // Q: M=16384, N=512, K=512 -> 128x2 blocks
    int bq = bx - 128;
    int bi = (bq & 7) * 32 + (bq >> 3);        // [0,256)
    gemm8p<0>(xb, wqT, Qb, nullptr, nullptr, 512, 512, qscale, bi & 1, bi >> 1, Ash, Bsh);
  }
}

// ---------------- output projection (fp32 out + bias) ----------------
__global__ __launch_bounds__(512, 2) void outproj(const u16* __restrict__ Ob, const u16* __restrict__ woT,
                                                  float* __restrict__ out, const float* __restrict__ bo) {
  __shared__ alignas(16) u16 Ash[3 * 8192];
  __shared__ alignas(16) u16 Bsh[3 * 16384];
  int bx = blockIdx.x;
  int bi = (bx & 7) * 32 + (bx >> 3);          // [0,256)
  gemm8p<1>(Ob, woT, out, nullptr, bo, 512, 512, 1.0f, bi & 1, bi >> 1, Ash, Bsh);
}

// ---------------- flash cross-attention: 64 q/wave, 4-wave blocks, 64-key tiles ----------------
// R9 = R8's 64 q/wave math (halved LDS demand, refcheck-passed) + R7's 256-thread/16-wave-CU
// occupancy (R8's 128-thread blocks left only 2 waves/SIMD -> Occupancy 15%, MfmaUtil fell).
// 256 threads = 4 waves x 64 q = 256 q/block; grid (16,8,4) = 512 = 2 blocks/CU,
// 16 waves/CU (4/SIMD), LDS 32KB x 2 = 64KB. Per-CU per-kt: MFMA ~18.6us total floor,
// LDS ~10us (halved vs R7), 2 independent barrier groups to overlap.
__global__ __launch_bounds__(256, 2) void attn(const u16* __restrict__ Q, const u16* __restrict__ Kb,
                                               const u16* __restrict__ Vt, u16* __restrict__ O) {
  __shared__ alignas(16) u16 Kl[2][64][64];   // 16 KB
  __shared__ alignas(16) u16 Vl[2][64][64];   // 16 KB
  int qt = blockIdx.x, h = blockIdx.y, b = blockIdx.z;
  int tid = threadIdx.x, wave = tid >> 6, lane = tid & 63, quad = lane >> 4, l16 = lane & 15;
  int q0 = qt * 256 + wave * 64;
  int x7 = l16 & 7;

  // staging (256 threads, R7-verified): row tid>>3 in [0,32), chunk (tid&7)^(row&7);
  // second call covers rows 32-63 (row&7 invariant -> same involution as read side).
  int kr = tid >> 3, kc = (tid & 7) ^ (kr & 7);
  const u16* kg = Kb + ((size_t)b * NC + kr) * 512 + h * DH + kc * 8;
  const u16* vg = Vt + ((size_t)(b * NH + h) * DH + kr) * NC + kc * 8;

#define ASTAGE(kt, buf) do { \
    const u16* kg_ = kg + (size_t)(kt) * 64 * 512; \
    const u16* vg_ = vg + (kt) * 64; \
    u16* kl_ = (u16*)Kl + (buf) * 4096; u16* vl_ = (u16*)Vl + (buf) * 4096; \
    g2l16(kg_,            kl_ + tid * 8); \
    g2l16(kg_ + 32 * 512, kl_ + (tid + 256) * 8); \
    g2l16(vg_,            vl_ + tid * 8); \
    g2l16(vg_ + 32 * NC,  vl_ + (tid + 256) * 8); } while (0)

  // Q B-frags for 4 n-subtiles x 2 dh-chunks, in regs for the whole kernel (32 VGPR)
  s8v aq[4][2];
  {
    const u16* Qp = Q + ((size_t)b * NQ + q0 + l16) * DI + h * DH + quad * 8;
    #pragma unroll
    for (int n = 0; n < 4; n++) {
      aq[n][0] = *(const s8v*)(Qp + (size_t)n * 16 * DI);
      aq[n][1] = *(const s8v*)(Qp + (size_t)n * 16 * DI + 32);
    }
  }
  s8v vones;
  #pragma unroll
  for (int i = 0; i < 8; i++) vones[i] = (short)0x3F80;

  f4v oacc[4][4];
  f4v lacc[4];
  #pragma unroll
  for (int d = 0; d < 4; d++)
    #pragma unroll
    for (int n = 0; n < 4; n++) oacc[d][n] = (f4v){0.f, 0.f, 0.f, 0.f};
  #pragma unroll
  for (int n = 0; n < 4; n++) lacc[n] = (f4v){0.f, 0.f, 0.f, 0.f};

  ASTAGE(0, 0);
  for (int kt = 0; kt < NC / 64; ++kt) {
    int buf = kt & 1;
    __syncthreads();
    if (kt + 1 < NC / 64) ASTAGE(kt + 1, buf ^ 1);
    const u16* kb = (const u16*)Kl + buf * 4096;
    const u16* vb = (const u16*)Vl + buf * 4096;

    // ---- QK^T for both 32-key chunks (8 ds_read_b128 + 32 MFMA) ----
    f4v S0[2][4], S1[2][4];
    #pragma unroll
    for (int mi = 0; mi < 2; mi++)
      #pragma unroll
      for (int n = 0; n < 4; n++) { S0[mi][n] = (f4v){0.f,0.f,0.f,0.f}; S1[mi][n] = (f4v){0.f,0.f,0.f,0.f}; }
    __builtin_amdgcn_s_setprio(1);
    #pragma unroll
    for (int cd = 0; cd < 2; cd++) {
      int ch = ((4 * cd + quad) ^ x7) * 8;
      s8v k00 = *(const s8v*)(kb + (l16     ) * 64 + ch);
      s8v k01 = *(const s8v*)(kb + (l16 + 16) * 64 + ch);
      #pragma unroll
      for (int n = 0; n < 4; n++) {
        S0[0][n] = __builtin_amdgcn_mfma_f32_16x16x32_bf16(k00, aq[n][cd], S0[0][n], 0, 0, 0);
        S0[1][n] = __builtin_amdgcn_mfma_f32_16x16x32_bf16(k01, aq[n][cd], S0[1][n], 0, 0, 0);
      }
      s8v k10 = *(const s8v*)(kb + (l16 + 32) * 64 + ch);
      s8v k11 = *(const s8v*)(kb + (l16 + 48) * 64 + ch);
      #pragma unroll
      for (int n = 0; n < 4; n++) {
        S1[0][n] = __builtin_amdgcn_mfma_f32_16x16x32_bf16(k10, aq[n][cd], S1[0][n], 0, 0, 0);
        S1[1][n] = __builtin_amdgcn_mfma_f32_16x16x32_bf16(k11, aq[n][cd], S1[1][n], 0, 0, 0);
      }
    }
    __builtin_amdgcn_s_setprio(0);

    // ---- softmax chunk 0 ----
    s8v pf0[4];
    #pragma unroll
    for (int n = 0; n < 4; n++) {
      float p00 = EXP2(S0[0][n][0]), p01 = EXP2(S0[0][n][1]), p02 = EXP2(S0[0][n][2]), p03 = EXP2(S0[0][n][3]);
      float p10 = EXP2(S0[1][n][0]), p11 = EXP2(S0[1][n][1]), p12 = EXP2(S0[1][n][2]), p13 = EXP2(S0[1][n][3]);
      union { u32 d[4]; s8v v; } u;
      u.d[0] = cvtpk(p00, p01); u.d[1] = cvtpk(p02, p03);
      u.d[2] = cvtpk(p10, p11); u.d[3] = cvtpk(p12, p13);
      pf0[n] = u.v;
    }
    // ---- PV chunk 0 + denominator ----
    __builtin_amdgcn_s_setprio(1);
    #pragma unroll
    for (int n = 0; n < 4; n++)
      lacc[n] = __builtin_amdgcn_mfma_f32_16x16x32_bf16(vones, pf0[n], lacc[n], 0, 0, 0);
    #pragma unroll
    for (int d = 0; d < 4; d++) {
      int ch = (quad ^ x7) * 8;
      s8v vf = *(const s8v*)(vb + (d * 16 + l16) * 64 + ch);
      #pragma unroll
      for (int n = 0; n < 4; n++)
        oacc[d][n] = __builtin_amdgcn_mfma_f32_16x16x32_bf16(vf, pf0[n], oacc[d][n], 0, 0, 0);
    }
    __builtin_amdgcn_s_setprio(0);

    // ---- softmax chunk 1 (overlaps PV c0) ----
    s8v pf1[4];
    #pragma unroll
    for (int n = 0; n < 4; n++) {
      float p00 = EXP2(S1[0][n][0]), p01 = EXP2(S1[0][n][1]), p02 = EXP2(S1[0][n][2]), p03 = EXP2(S1[0][n][3]);
      float p10 = EXP2(S1[1][n][0]), p11 = EXP2(S1[1][n][1]), p12 = EXP2(S1[1][n][2]), p13 = EXP2(S1[1][n][3]);
      union { u32 d[4]; s8v v; } u;
      u.d[0] = cvtpk(p00, p01); u.d[1] = cvtpk(p02, p03);
      u.d[2] = cvtpk(p10, p11); u.d[3] = cvtpk(p12, p13);
      pf1[n] = u.v;
    }
    // ---- PV chunk 1 + denominator ----
    __builtin_amdgcn_s_setprio(1);
    #pragma unroll
    for (int n = 0; n < 4; n++)
      lacc[n] = __builtin_amdgcn_mfma_f32_16x16x32_bf16(vones, pf1[n], lacc[n], 0, 0, 0);
    #pragma unroll
    for (int d = 0; d < 4; d++) {
      int ch = ((4 + quad) ^ x7) * 8;
      s8v vf = *(const s8v*)(vb + (d * 16 + l16) * 64 + ch);
      #pragma unroll
      for (int n = 0; n < 4; n++)
        oacc[d][n] = __builtin_amdgcn_mfma_f32_16x16x32_bf16(vf, pf1[n], oacc[d][n], 0, 0, 0);
    }
    __builtin_amdgcn_s_setprio(0);
  }
#undef ASTAGE

  float inv[4];
  #pragma unroll
  for (int n = 0; n < 4; n++) inv[n] = 1.0f / lacc[n][0];

  #pragma unroll
  for (int d = 0; d < 4; d++)
    #pragma unroll
    for (int n = 0; n < 4; n++) {
      int q = q0 + n * 16 + l16;
      uint2 ov;
      ov.x = cvtpk(oacc[d][n][0] * inv[n], oacc[d][n][1] * inv[n]);
      ov.y = cvtpk(oacc[d][n][2] * inv[n], oacc[d][n][3] * inv[n]);
      *(uint2*)(O + ((size_t)b * NQ + q) * DI + h * DH + d * 16 + quad * 4) = ov;
    }
}

extern "C" void kernel_launch(void* const* d_in, const int* in_sizes, int n_in,
                              void* d_out, int out_size, void* d_ws, size_t ws_size,
                              hipStream_t stream) {
  const float* x   = (const float*)d_in[0];
  const float* ctx = (const float*)d_in[1];
  const float* Wq  = (const float*)d_in[2];
  const float* Wk  = (const float*)d_in[3];
  const float* Wv  = (const float*)d_in[4];
  const float* Wo  = (const float*)d_in[5];
  const float* bo  = (const float*)d_in[6];
  float* out = (float*)d_out;

  u16* w    = (u16*)d_ws;                // workspace layout (bf16 elems)
  u16* xb   = w;                         // 8388608
  u16* cb   = xb   + 8388608;            // 3145728
  u16* wqT  = cb   + 3145728;            // 262144
  u16* wkvT = wqT  + 262144;             // 786432 (Wk^T rows 0-511, Wv^T rows 512-1023)
  u16* woT  = wkvT + 786432;             // 262144
  u16* Qb   = woT  + 262144;             // 8388608 (pre-scaled by 0.125*log2e)
  u16* Kbuf = Qb   + 8388608;            // 2097152 ([b*1024+t][512])
  u16* Vtb  = Kbuf + 2097152;            // 2097152 (key-permuted V^T)
  u16* Ob   = Vtb  + 2097152;            // 8388608

  const float qscale = 0.125f * 1.44269504f;  // softmax scale + log2(e) folded into Q

  prep<<<11648, 256, 0, stream>>>(x, ctx, Wq, Wk, Wv, Wo, xb, cb, wqT, wkvT, woT);
  proj_all<<<384, 512, 0, stream>>>(xb, cb, wqT, wkvT, Qb, Kbuf, Vtb, qscale);
  attn<<<dim3(16, 8, 4), 256, 0, stream>>>(Qb, Kbuf, Vtb, Ob);
  outproj<<<256, 512, 0, stream>>>(Ob, woT, out, bo);
}

// Round 10
// 178.156 us; speedup vs baseline: 1.0513x; 1.0093x over previous
//
#include <hip/hip_runtime.h>
#include <math.h>

typedef __attribute__((ext_vector_type(8))) short s8v;   // 8 x bf16 (4 VGPRs) — MFMA A/B frag
typedef __attribute__((ext_vector_type(4))) float f4v;   // 4 x fp32 — MFMA C/D frag
typedef unsigned short u16;
typedef unsigned int u32;

constexpr int Bsz = 4, NQ = 4096, NC = 1024, NH = 8, DH = 64, DI = 512, DC = 768;

__device__ __forceinline__ u16 f2bf(float f) {
  union { float f; u32 u; } v; v.f = f;
  u32 r = v.u + 0x7fff + ((v.u >> 16) & 1);  // RNE
  return (u16)(r >> 16);
}

__device__ __forceinline__ u32 pack2(float a, float b) {
  union { float f; u32 u; } ua, ub; ua.f = a; ub.f = b;
#if __has_builtin(__builtin_amdgcn_perm)
  return __builtin_amdgcn_perm(ub.u + 0x8000u, ua.u + 0x8000u, 0x07060302u);
#else
  return ((ub.u + 0x8000u) & 0xffff0000u) | ((ua.u + 0x8000u) >> 16);
#endif
}

// single-instruction RNE pack (v_cvt_pk_bf16_f32)
__device__ __forceinline__ u32 cvtpk(float a, float b) {
  u32 r;
  asm("v_cvt_pk_bf16_f32 %0, %1, %2" : "=v"(r) : "v"(a), "v"(b));
  return r;
}

#if __has_builtin(__builtin_amdgcn_exp2f)
#define EXP2(x) __builtin_amdgcn_exp2f(x)
#else
#define EXP2(x) exp2f(x)
#endif

// async global->LDS, 16B per lane (m97 pattern)
__device__ __forceinline__ void g2l16(const void* g, void* l) {
  __builtin_amdgcn_global_load_lds((const __attribute__((address_space(1))) u32*)g,
                                   (__attribute__((address_space(3))) u32*)l, 16, 0, 0);
}

// ---------------- prep: casts + all weight transposes in one launch (R0-verified) --------
__global__ __launch_bounds__(256) void prep(const float* __restrict__ x, const float* __restrict__ ctx,
                                            const float* __restrict__ Wq, const float* __restrict__ Wk,
                                            const float* __restrict__ Wv, const float* __restrict__ Wo,
                                            u16* __restrict__ xb, u16* __restrict__ cb,
                                            u16* __restrict__ wqT, u16* __restrict__ wkvT,
                                            u16* __restrict__ woT) {
  int bx = blockIdx.x;
  if (bx < 11264) {                       // cast path: x then ctx, float4-vectorized
    const int NX4 = Bsz * NQ * DI / 4;    // 2097152
    const int NC4 = Bsz * NC * DC / 4;    // 786432
    int i = bx * 256 + threadIdx.x;
    float4 v; u16* dst; int j;
    if (i < NX4) { v = ((const float4*)x)[i]; dst = xb; j = i; }
    else { j = i - NX4; if (j >= NC4) return; v = ((const float4*)ctx)[j]; dst = cb; }
    ushort4 o; o.x = f2bf(v.x); o.y = f2bf(v.y); o.z = f2bf(v.z); o.w = f2bf(v.w);
    ((ushort4*)dst)[j] = o;
    return;
  }
  int idx = bx - 11264;                   // [0,384): weight transpose W[K][N] -> W^T[N][K] bf16
  int z = idx / 96, rem = idx % 96, kx = rem % 12, ny = rem / 12;
  const float* src; u16* dst; int K; const int N = 512;
  if (z == 0)      { src = Wq; dst = wqT;              K = 512; }
  else if (z == 1) { src = Wk; dst = wkvT;             K = 768; }
  else if (z == 2) { src = Wv; dst = wkvT + 512 * 768; K = 768; }
  else             { src = Wo; dst = woT;              K = 512; }
  int k0 = kx * 64, n0 = ny * 64;
  if (k0 >= K) return;
  __shared__ u16 t[64][65];
  int tid = threadIdx.x, jr = tid & 63, ir = tid >> 6;
  for (int it = 0; it < 16; ++it) { int i = it * 4 + ir; t[i][jr] = f2bf(src[(size_t)(k0 + i) * N + n0 + jr]); }
  __syncthreads();
  for (int it = 0; it < 16; ++it) { int i = it * 4 + ir; dst[(size_t)(n0 + i) * K + k0 + jr] = t[jr][i]; }
}

// ---------------- 8-phase GEMM body: 128x256 tile, BK=64, 512 threads, 8 waves ----------------
// (R7-verified: T3+T4 8-phase counted-vmcnt schedule; 3 K-tile LDS buffers; vmcnt(6) at
// phases 4/8 only; XOR-chunk swizzle both-sides involution; setprio around MFMA clusters.)
template <int MODE>
__device__ __forceinline__ void gemm8p(const u16* __restrict__ A, const u16* __restrict__ Bt,
                                       void* __restrict__ C0, void* __restrict__ C1,
                                       const float* __restrict__ bias, int N, int K,
                                       float oscale, int nbx, int mby,
                                       u16* Ash, u16* Bsh) {   // Ash: 3*8192, Bsh: 3*16384 (u16)
  int tid = threadIdx.x;                  // 0..511
  int lane = tid & 63, quad = lane >> 4, l16 = lane & 15, wave = tid >> 6;
  int wm = (wave >> 2) * 64, wn = (wave & 3) * 64;   // 2M x 4N wave grid; 64x64 per wave
  int mb = mby * 128, nb = nbx * 256;
  int x7 = l16 & 7;
  f4v acc[4][4];
  #pragma unroll
  for (int i = 0; i < 4; i++)
    #pragma unroll
    for (int j = 0; j < 4; j++) acc[i][j] = (f4v){0.f, 0.f, 0.f, 0.f};

  int srow = tid >> 3;
  int sc = ((tid & 7) ^ (srow & 7)) * 8;
  const u16* Ap0 = A  + (size_t)(mb + srow) * K + sc;
  const u16* Bq0 = Bt + (size_t)(nb + srow) * K + sc;
  int lin = tid * 8;

#define SA(ts, dst) do { const u16* s_ = Ap0 + (size_t)(ts) * 64; \
    g2l16(s_, (dst) + lin); g2l16(s_ + (size_t)64 * K, (dst) + 4096 + lin); } while (0)
#define SB0(ts, dst) do { const u16* s_ = Bq0 + (size_t)(ts) * 64; \
    g2l16(s_, (dst) + lin); g2l16(s_ + (size_t)64 * K, (dst) + 4096 + lin); } while (0)
#define SB1(ts, dst) do { const u16* s_ = Bq0 + (size_t)(ts) * 64 + (size_t)128 * K; \
    g2l16(s_, (dst) + 8192 + lin); g2l16(s_ + (size_t)64 * K, (dst) + 12288 + lin); } while (0)

  int ak0 = ((0 + quad) ^ x7) * 8;
  int ak1 = ((4 + quad) ^ x7) * 8;

  s8v bfr[4];
#define PHASE(ABUF, BBUF, AKK, IP, LOADB, WAITN, ...) do { \
    if (LOADB) { \
      bfr[0] = *(const s8v*)((BBUF) + (wn +  0 + l16) * 64 + (AKK)); \
      bfr[1] = *(const s8v*)((BBUF) + (wn + 16 + l16) * 64 + (AKK)); \
      bfr[2] = *(const s8v*)((BBUF) + (wn + 32 + l16) * 64 + (AKK)); \
      bfr[3] = *(const s8v*)((BBUF) + (wn + 48 + l16) * 64 + (AKK)); \
    } \
    s8v af0 = *(const s8v*)((ABUF) + (wm + (IP) * 32 + l16) * 64 + (AKK)); \
    s8v af1 = *(const s8v*)((ABUF) + (wm + (IP) * 32 + 16 + l16) * 64 + (AKK)); \
    __VA_ARGS__; \
    { int wv_ = (WAITN); \
      if (wv_ == 6) asm volatile("s_waitcnt vmcnt(6)" ::: "memory"); \
      else if (wv_ == 0) asm volatile("s_waitcnt vmcnt(0)" ::: "memory"); } \
    asm volatile("" ::: "memory"); __builtin_amdgcn_s_barrier(); asm volatile("" ::: "memory"); \
    __builtin_amdgcn_s_setprio(1); \
    _Pragma("unroll") \
    for (int j = 0; j < 4; j++) { \
      acc[(IP)*2][j]   = __builtin_amdgcn_mfma_f32_16x16x32_bf16(af0, bfr[j], acc[(IP)*2][j],   0, 0, 0); \
      acc[(IP)*2+1][j] = __builtin_amdgcn_mfma_f32_16x16x32_bf16(af1, bfr[j], acc[(IP)*2+1][j], 0, 0, 0); \
    } \
    __builtin_amdgcn_s_setprio(0); \
    asm volatile("" ::: "memory"); __builtin_amdgcn_s_barrier(); asm volatile("" ::: "memory"); \
  } while (0)

  u16 *A0 = Ash, *A1 = Ash + 8192, *A2 = Ash + 16384;
  u16 *B0 = Bsh, *B1 = Bsh + 16384, *B2 = Bsh + 32768;

  SA(0, A0); SB0(0, B0); SB1(0, B0);
  SA(1, A1); SB0(1, B1); SB1(1, B1);
  asm volatile("s_waitcnt vmcnt(6)" ::: "memory");
  __builtin_amdgcn_s_barrier();
  asm volatile("" ::: "memory");

  int nkt = K >> 6;
  for (int t2 = 0; t2 < nkt; t2 += 2) {
    bool more = (t2 + 2 < nkt);
    PHASE(A0, B0, ak0, 0, true,  -1, if (more) SA(t2 + 2, A2));
    PHASE(A0, B0, ak0, 1, false, -1, if (more) SB0(t2 + 2, B2));
    PHASE(A0, B0, ak1, 0, true,  -1, if (more) SB1(t2 + 2, B2));
    PHASE(A0, B0, ak1, 1, false, (more ? 6 : 0), );
    PHASE(A1, B1, ak0, 0, true,  -1, if (more) SA(t2 + 3, A0));
    PHASE(A1, B1, ak0, 1, false, -1, if (more) SB0(t2 + 3, B0));
    PHASE(A1, B1, ak1, 0, true,  -1, if (more) SB1(t2 + 3, B0));
    PHASE(A1, B1, ak1, 1, false, (more ? 6 : -1), );
    u16* tA = A0; A0 = A2; A2 = A1; A1 = tA;
    u16* tB = B0; B0 = B2; B2 = B1; B1 = tB;
  }
#undef PHASE
#undef SA
#undef SB0
#undef SB1

  #pragma unroll
  for (int i = 0; i < 4; i++) {
    int rbase = mb + wm + i * 16 + quad * 4;
    #pragma unroll
    for (int j = 0; j < 4; j++) {
      int col = nb + wn + j * 16 + l16;
      if (MODE == 0) {
        u16* Cb = (u16*)C0;
        #pragma unroll
        for (int r = 0; r < 4; r++) Cb[(size_t)(rbase + r) * N + col] = f2bf(acc[i][j][r] * oscale);
      } else if (MODE == 1) {
        float* Cf = (float*)C0;
        #pragma unroll
        for (int r = 0; r < 4; r++) Cf[(size_t)(rbase + r) * N + col] = acc[i][j][r] + bias[col];
      } else {
        if (col < 512) {                  // K projection -> Kb [b*NC+t][512]
          u16* Kb = (u16*)C0;
          #pragma unroll
          for (int r = 0; r < 4; r++) Kb[(size_t)(rbase + r) * 512 + col] = f2bf(acc[i][j][r]);
        } else {                          // V projection -> Vt, transposed + key-permuted
          u16* Vt = (u16*)C1;
          int hd = col - 512, h = hd >> 6, d = hd & 63;
          int bb = rbase >> 10, tl = rbase & 1023;
          int tbase = tl & ~63, a0 = tl & 63;
          int pb = (a0 & 32) + ((a0 & 15) >> 2) * 8 + (((a0 >> 4) & 1) << 2);
          uint2 ov;
          ov.x = pack2(acc[i][j][0], acc[i][j][1]);
          ov.y = pack2(acc[i][j][2], acc[i][j][3]);
          *(uint2*)(Vt + ((size_t)(bb * NH + h) * DH + d) * NC + tbase + pb) = ov;
        }
      }
    }
  }
}

// ---------------- fused QKV projection (bf16 A from prep), XCD-chunked, KV first ----------------
__global__ __launch_bounds__(512, 2) void proj_all(const u16* __restrict__ xb, const u16* __restrict__ cb,
                                                   const u16* __restrict__ wqT, const u16* __restrict__ wkvT,
                                                   u16* __restrict__ Qb, u16* __restrict__ Kb,
                                                   u16* __restrict__ Vtb, float qscale) {
  __shared__ alignas(16) u16 Ash[3 * 8192];    // 48 KB
  __shared__ alignas(16) u16 Bsh[3 * 16384];   // 96 KB
  int bx = blockIdx.x;
  if (bx < 128) {  // KV: M=4096, N=1024, K=768 -> 32x4 blocks of 128x256
    int bi = (bx & 7) * 16 + (bx >> 3);        // XCD-chunked [0,128)
    gemm8p<2>(cb, wkvT, Kb, Vtb, nullptr, 1024, 768, 1.0f, bi & 3, bi >> 2, Ash, Bsh);
  } else {         // Q: M=16384, N=512, K=512 -> 128x2 blocks
    int bq = bx - 128;
    int bi = (bq & 7) * 32 + (bq >> 3);        // [0,256)
    gemm8p<0>(xb, wqT, Qb, nullptr, nullptr, 512, 512, qscale, bi & 1, bi >> 1, Ash, Bsh);
  }
}

// ---------------- output projection (fp32 out + bias) ----------------
__global__ __launch_bounds__(512, 2) void outproj(const u16* __restrict__ Ob, const u16* __restrict__ woT,
                                                  float* __restrict__ out, const float* __restrict__ bo) {
  __shared__ alignas(16) u16 Ash[3 * 8192];
  __shared__ alignas(16) u16 Bsh[3 * 16384];
  int bx = blockIdx.x;
  int bi = (bx & 7) * 32 + (bx >> 3);          // [0,256)
  gemm8p<1>(Ob, woT, out, nullptr, bo, 512, 512, 1.0f, bi & 1, bi >> 1, Ash, Bsh);
}

// ---------------- flash cross-attention: 64 q/wave, 4-wave blocks, 64-key tiles ----------------
// R10 changes vs R9 (counters: MfmaUtil 33.7 / VALUBusy 31.8 / neither pipe saturated ->
// phase-locked bursts: fused S0+S1 cd-loop forced 32-MFMA burst, then pure-TRANS exp burst):
//  * stage-split interleave: QK0 -> SM0 -> QK1 -> PV0 -> SM1 -> PV1. S0 completes after QK0,
//    so SM0's exp2 (TRANS) co-issues with QK1's MFMAs; SM1 overlaps PV0's tail. Same math,
//    pure reorder. lacc MFMA moved after oacc d-loop (critical pf->O path first).
//  * XCD-chunked grid (T1): 1-D grid 512, bi=(bx&7)*64+(bx>>3) -> each XCD owns all 16
//    qt-blocks of 4 (h,b) pairs -> K/V panel (512KB) fetched once per XCD, not 8x
//    (R9 FETCH 41MB vs 8MB ideal).
__global__ __launch_bounds__(256, 2) void attn(const u16* __restrict__ Q, const u16* __restrict__ Kb,
                                               const u16* __restrict__ Vt, u16* __restrict__ O) {
  __shared__ alignas(16) u16 Kl[2][64][64];   // 16 KB
  __shared__ alignas(16) u16 Vl[2][64][64];   // 16 KB
  int bx = blockIdx.x;
  int bi = (bx & 7) * 64 + (bx >> 3);         // bijective XCD chunking (512 % 8 == 0)
  int qt = bi & 15, h = (bi >> 4) & 7, b = bi >> 7;
  int tid = threadIdx.x, wave = tid >> 6, lane = tid & 63, quad = lane >> 4, l16 = lane & 15;
  int q0 = qt * 256 + wave * 64;
  int x7 = l16 & 7;

  int kr = tid >> 3, kc = (tid & 7) ^ (kr & 7);
  const u16* kg = Kb + ((size_t)b * NC + kr) * 512 + h * DH + kc * 8;
  const u16* vg = Vt + ((size_t)(b * NH + h) * DH + kr) * NC + kc * 8;

#define ASTAGE(kt, buf) do { \
    const u16* kg_ = kg + (size_t)(kt) * 64 * 512; \
    const u16* vg_ = vg + (kt) * 64; \
    u16* kl_ = (u16*)Kl + (buf) * 4096; u16* vl_ = (u16*)Vl + (buf) * 4096; \
    g2l16(kg_,            kl_ + tid * 8); \
    g2l16(kg_ + 32 * 512, kl_ + (tid + 256) * 8); \
    g2l16(vg_,            vl_ + tid * 8); \
    g2l16(vg_ + 32 * NC,  vl_ + (tid + 256) * 8); } while (0)

  // Q B-frags for 4 n-subtiles x 2 dh-chunks, in regs for the whole kernel (32 VGPR)
  s8v aq[4][2];
  {
    const u16* Qp = Q + ((size_t)b * NQ + q0 + l16) * DI + h * DH + quad * 8;
    #pragma unroll
    for (int n = 0; n < 4; n++) {
      aq[n][0] = *(const s8v*)(Qp + (size_t)n * 16 * DI);
      aq[n][1] = *(const s8v*)(Qp + (size_t)n * 16 * DI + 32);
    }
  }
  s8v vones;
  #pragma unroll
  for (int i = 0; i < 8; i++) vones[i] = (short)0x3F80;

  f4v oacc[4][4];
  f4v lacc[4];
  #pragma unroll
  for (int d = 0; d < 4; d++)
    #pragma unroll
    for (int n = 0; n < 4; n++) oacc[d][n] = (f4v){0.f, 0.f, 0.f, 0.f};
  #pragma unroll
  for (int n = 0; n < 4; n++) lacc[n] = (f4v){0.f, 0.f, 0.f, 0.f};

  ASTAGE(0, 0);
  for (int kt = 0; kt < NC / 64; ++kt) {
    int buf = kt & 1;
    __syncthreads();
    if (kt + 1 < NC / 64) ASTAGE(kt + 1, buf ^ 1);
    const u16* kb = (const u16*)Kl + buf * 4096;
    const u16* vb = (const u16*)Vl + buf * 4096;

    // ---- QK chunk 0 (keys 0-31): S0 complete after this stage ----
    f4v S0[2][4];
    #pragma unroll
    for (int mi = 0; mi < 2; mi++)
      #pragma unroll
      for (int n = 0; n < 4; n++) S0[mi][n] = (f4v){0.f,0.f,0.f,0.f};
    __builtin_amdgcn_s_setprio(1);
    #pragma unroll
    for (int cd = 0; cd < 2; cd++) {
      int ch = ((4 * cd + quad) ^ x7) * 8;
      s8v k00 = *(const s8v*)(kb + (l16     ) * 64 + ch);
      s8v k01 = *(const s8v*)(kb + (l16 + 16) * 64 + ch);
      #pragma unroll
      for (int n = 0; n < 4; n++) {
        S0[0][n] = __builtin_amdgcn_mfma_f32_16x16x32_bf16(k00, aq[n][cd], S0[0][n], 0, 0, 0);
        S0[1][n] = __builtin_amdgcn_mfma_f32_16x16x32_bf16(k01, aq[n][cd], S0[1][n], 0, 0, 0);
      }
    }
    __builtin_amdgcn_s_setprio(0);

    // ---- softmax chunk 0 (TRANS stream; co-issues with QK1's MFMAs below) ----
    s8v pf0[4];
    #pragma unroll
    for (int n = 0; n < 4; n++) {
      float p00 = EXP2(S0[0][n][0]), p01 = EXP2(S0[0][n][1]), p02 = EXP2(S0[0][n][2]), p03 = EXP2(S0[0][n][3]);
      float p10 = EXP2(S0[1][n][0]), p11 = EXP2(S0[1][n][1]), p12 = EXP2(S0[1][n][2]), p13 = EXP2(S0[1][n][3]);
      union { u32 d[4]; s8v v; } u;
      u.d[0] = cvtpk(p00, p01); u.d[1] = cvtpk(p02, p03);
      u.d[2] = cvtpk(p10, p11); u.d[3] = cvtpk(p12, p13);
      pf0[n] = u.v;
    }

    // ---- QK chunk 1 (keys 32-63) ----
    f4v S1[2][4];
    #pragma unroll
    for (int mi = 0; mi < 2; mi++)
      #pragma unroll
      for (int n = 0; n < 4; n++) S1[mi][n] = (f4v){0.f,0.f,0.f,0.f};
    __builtin_amdgcn_s_setprio(1);
    #pragma unroll
    for (int cd = 0; cd < 2; cd++) {
      int ch = ((4 * cd + quad) ^ x7) * 8;
      s8v k10 = *(const s8v*)(kb + (l16 + 32) * 64 + ch);
      s8v k11 = *(const s8v*)(kb + (l16 + 48) * 64 + ch);
      #pragma unroll
      for (int n = 0; n < 4; n++) {
        S1[0][n] = __builtin_amdgcn_mfma_f32_16x16x32_bf16(k10, aq[n][cd], S1[0][n], 0, 0, 0);
        S1[1][n] = __builtin_amdgcn_mfma_f32_16x16x32_bf16(k11, aq[n][cd], S1[1][n], 0, 0, 0);
      }
    }
    __builtin_amdgcn_s_setprio(0);

    // ---- PV chunk 0 (oacc first; lacc after) ----
    __builtin_amdgcn_s_setprio(1);
    #pragma unroll
    for (int d = 0; d < 4; d++) {
      int ch = (quad ^ x7) * 8;
      s8v vf = *(const s8v*)(vb + (d * 16 + l16) * 64 + ch);
      #pragma unroll
      for (int n = 0; n < 4; n++)
        oacc[d][n] = __builtin_amdgcn_mfma_f32_16x16x32_bf16(vf, pf0[n], oacc[d][n], 0, 0, 0);
    }
    #pragma unroll
    for (int n = 0; n < 4; n++)
      lacc[n] = __builtin_amdgcn_mfma_f32_16x16x32_bf16(vones, pf0[n], lacc[n], 0, 0, 0);
    __builtin_amdgcn_s_setprio(0);

    // ---- softmax chunk 1 (overlaps PV c0 tail) ----
    s8v pf1[4];
    #pragma unroll
    for (int n = 0; n < 4; n++) {
      float p00 = EXP2(S1[0][n][0]), p01 = EXP2(S1[0][n][1]), p02 = EXP2(S1[0][n][2]), p03 = EXP2(S1[0][n][3]);
      float p10 = EXP2(S1[1][n][0]), p11 = EXP2(S1[1][n][1]), p12 = EXP2(S1[1][n][2]), p13 = EXP2(S1[1][n][3]);
      union { u32 d[4]; s8v v; } u;
      u.d[0] = cvtpk(p00, p01); u.d[1] = cvtpk(p02, p03);
      u.d[2] = cvtpk(p10, p11); u.d[3] = cvtpk(p12, p13);
      pf1[n] = u.v;
    }
    // ---- PV chunk 1 ----
    __builtin_amdgcn_s_setprio(1);
    #pragma unroll
    for (int d = 0; d < 4; d++) {
      int ch = ((4 + quad) ^ x7) * 8;
      s8v vf = *(const s8v*)(vb + (d * 16 + l16) * 64 + ch);
      #pragma unroll
      for (int n = 0; n < 4; n++)
        oacc[d][n] = __builtin_amdgcn_mfma_f32_16x16x32_bf16(vf, pf1[n], oacc[d][n], 0, 0, 0);
    }
    #pragma unroll
    for (int n = 0; n < 4; n++)
      lacc[n] = __builtin_amdgcn_mfma_f32_16x16x32_bf16(vones, pf1[n], lacc[n], 0, 0, 0);
    __builtin_amdgcn_s_setprio(0);
  }
#undef ASTAGE

  float inv[4];
  #pragma unroll
  for (int n = 0; n < 4; n++) inv[n] = 1.0f / lacc[n][0];

  #pragma unroll
  for (int d = 0; d < 4; d++)
    #pragma unroll
    for (int n = 0; n < 4; n++) {
      int q = q0 + n * 16 + l16;
      uint2 ov;
      ov.x = cvtpk(oacc[d][n][0] * inv[n], oacc[d][n][1] * inv[n]);
      ov.y = cvtpk(oacc[d][n][2] * inv[n], oacc[d][n][3] * inv[n]);
      *(uint2*)(O + ((size_t)b * NQ + q) * DI + h * DH + d * 16 + quad * 4) = ov;
    }
}

extern "C" void kernel_launch(void* const* d_in, const int* in_sizes, int n_in,
                              void* d_out, int out_size, void* d_ws, size_t ws_size,
                              hipStream_t stream) {
  const float* x   = (const float*)d_in[0];
  const float* ctx = (const float*)d_in[1];
  const float* Wq  = (const float*)d_in[2];
  const float* Wk  = (const float*)d_in[3];
  const float* Wv  = (const float*)d_in[4];
  const float* Wo  = (const float*)d_in[5];
  const float* bo  = (const float*)d_in[6];
  float* out = (float*)d_out;

  u16* w    = (u16*)d_ws;                // workspace layout (bf16 elems)
  u16* xb   = w;                         // 8388608
  u16* cb   = xb   + 8388608;            // 3145728
  u16* wqT  = cb   + 3145728;            // 262144
  u16* wkvT = wqT  + 262144;             // 786432 (Wk^T rows 0-511, Wv^T rows 512-1023)
  u16* woT  = wkvT + 786432;             // 262144
  u16* Qb   = woT  + 262144;             // 8388608 (pre-scaled by 0.125*log2e)
  u16* Kbuf = Qb   + 8388608;            // 2097152 ([b*1024+t][512])
  u16* Vtb  = Kbuf + 2097152;            // 2097152 (key-permuted V^T)
  u16* Ob   = Vtb  + 2097152;            // 8388608

  const float qscale = 0.125f * 1.44269504f;  // softmax scale + log2(e) folded into Q

  prep<<<11648, 256, 0, stream>>>(x, ctx, Wq, Wk, Wv, Wo, xb, cb, wqT, wkvT, woT);
  proj_all<<<384, 512, 0, stream>>>(xb, cb, wqT, wkvT, Qb, Kbuf, Vtb, qscale);
  attn<<<512, 256, 0, stream>>>(Qb, Kbuf, Vtb, Ob);
  outproj<<<256, 512, 0, stream>>>(Ob, woT, out, bo);
}

// Round 11
// 176.315 us; speedup vs baseline: 1.0623x; 1.0104x over previous
//
#include <hip/hip_runtime.h>
#include <math.h>

typedef __attribute__((ext_vector_type(8))) short s8v;   // 8 x bf16 (4 VGPRs) — MFMA A/B frag
typedef __attribute__((ext_vector_type(4))) float f4v;   // 4 x fp32 — MFMA C/D frag
typedef unsigned short u16;
typedef unsigned int u32;

constexpr int Bsz = 4, NQ = 4096, NC = 1024, NH = 8, DH = 64, DI = 512, DC = 768;

__device__ __forceinline__ u16 f2bf(float f) {
  union { float f; u32 u; } v; v.f = f;
  u32 r = v.u + 0x7fff + ((v.u >> 16) & 1);  // RNE
  return (u16)(r >> 16);
}

__device__ __forceinline__ u32 pack2(float a, float b) {
  union { float f; u32 u; } ua, ub; ua.f = a; ub.f = b;
#if __has_builtin(__builtin_amdgcn_perm)
  return __builtin_amdgcn_perm(ub.u + 0x8000u, ua.u + 0x8000u, 0x07060302u);
#else
  return ((ub.u + 0x8000u) & 0xffff0000u) | ((ua.u + 0x8000u) >> 16);
#endif
}

// single-instruction RNE pack (v_cvt_pk_bf16_f32)
__device__ __forceinline__ u32 cvtpk(float a, float b) {
  u32 r;
  asm("v_cvt_pk_bf16_f32 %0, %1, %2" : "=v"(r) : "v"(a), "v"(b));
  return r;
}

#if __has_builtin(__builtin_amdgcn_exp2f)
#define EXP2(x) __builtin_amdgcn_exp2f(x)
#else
#define EXP2(x) exp2f(x)
#endif

// async global->LDS, 16B per lane (m97 pattern)
__device__ __forceinline__ void g2l16(const void* g, void* l) {
  __builtin_amdgcn_global_load_lds((const __attribute__((address_space(1))) u32*)g,
                                   (__attribute__((address_space(3))) u32*)l, 16, 0, 0);
}

// ---------------- prep: casts + all weight transposes in one launch (R0-verified) --------
__global__ __launch_bounds__(256) void prep(const float* __restrict__ x, const float* __restrict__ ctx,
                                            const float* __restrict__ Wq, const float* __restrict__ Wk,
                                            const float* __restrict__ Wv, const float* __restrict__ Wo,
                                            u16* __restrict__ xb, u16* __restrict__ cb,
                                            u16* __restrict__ wqT, u16* __restrict__ wkvT,
                                            u16* __restrict__ woT) {
  int bx = blockIdx.x;
  if (bx < 11264) {                       // cast path: x then ctx, float4-vectorized
    const int NX4 = Bsz * NQ * DI / 4;    // 2097152
    const int NC4 = Bsz * NC * DC / 4;    // 786432
    int i = bx * 256 + threadIdx.x;
    float4 v; u16* dst; int j;
    if (i < NX4) { v = ((const float4*)x)[i]; dst = xb; j = i; }
    else { j = i - NX4; if (j >= NC4) return; v = ((const float4*)ctx)[j]; dst = cb; }
    ushort4 o; o.x = f2bf(v.x); o.y = f2bf(v.y); o.z = f2bf(v.z); o.w = f2bf(v.w);
    ((ushort4*)dst)[j] = o;
    return;
  }
  int idx = bx - 11264;                   // [0,384): weight transpose W[K][N] -> W^T[N][K] bf16
  int z = idx / 96, rem = idx % 96, kx = rem % 12, ny = rem / 12;
  const float* src; u16* dst; int K; const int N = 512;
  if (z == 0)      { src = Wq; dst = wqT;              K = 512; }
  else if (z == 1) { src = Wk; dst = wkvT;             K = 768; }
  else if (z == 2) { src = Wv; dst = wkvT + 512 * 768; K = 768; }
  else             { src = Wo; dst = woT;              K = 512; }
  int k0 = kx * 64, n0 = ny * 64;
  if (k0 >= K) return;
  __shared__ u16 t[64][65];
  int tid = threadIdx.x, jr = tid & 63, ir = tid >> 6;
  for (int it = 0; it < 16; ++it) { int i = it * 4 + ir; t[i][jr] = f2bf(src[(size_t)(k0 + i) * N + n0 + jr]); }
  __syncthreads();
  for (int it = 0; it < 16; ++it) { int i = it * 4 + ir; dst[(size_t)(n0 + i) * K + k0 + jr] = t[jr][i]; }
}

// ---------------- 8-phase GEMM body: 128x256 tile, BK=64, 512 threads, 8 waves ----------------
// (R7-verified: T3+T4 8-phase counted-vmcnt schedule; 3 K-tile LDS buffers; vmcnt(6) at
// phases 4/8 only; XOR-chunk swizzle both-sides involution; setprio around MFMA clusters.)
template <int MODE>
__device__ __forceinline__ void gemm8p(const u16* __restrict__ A, const u16* __restrict__ Bt,
                                       void* __restrict__ C0, void* __restrict__ C1,
                                       const float* __restrict__ bias, int N, int K,
                                       float oscale, int nbx, int mby,
                                       u16* Ash, u16* Bsh) {   // Ash: 3*8192, Bsh: 3*16384 (u16)
  int tid = threadIdx.x;                  // 0..511
  int lane = tid & 63, quad = lane >> 4, l16 = lane & 15, wave = tid >> 6;
  int wm = (wave >> 2) * 64, wn = (wave & 3) * 64;   // 2M x 4N wave grid; 64x64 per wave
  int mb = mby * 128, nb = nbx * 256;
  int x7 = l16 & 7;
  f4v acc[4][4];
  #pragma unroll
  for (int i = 0; i < 4; i++)
    #pragma unroll
    for (int j = 0; j < 4; j++) acc[i][j] = (f4v){0.f, 0.f, 0.f, 0.f};

  int srow = tid >> 3;
  int sc = ((tid & 7) ^ (srow & 7)) * 8;
  const u16* Ap0 = A  + (size_t)(mb + srow) * K + sc;
  const u16* Bq0 = Bt + (size_t)(nb + srow) * K + sc;
  int lin = tid * 8;

#define SA(ts, dst) do { const u16* s_ = Ap0 + (size_t)(ts) * 64; \
    g2l16(s_, (dst) + lin); g2l16(s_ + (size_t)64 * K, (dst) + 4096 + lin); } while (0)
#define SB0(ts, dst) do { const u16* s_ = Bq0 + (size_t)(ts) * 64; \
    g2l16(s_, (dst) + lin); g2l16(s_ + (size_t)64 * K, (dst) + 4096 + lin); } while (0)
#define SB1(ts, dst) do { const u16* s_ = Bq0 + (size_t)(ts) * 64 + (size_t)128 * K; \
    g2l16(s_, (dst) + 8192 + lin); g2l16(s_ + (size_t)64 * K, (dst) + 12288 + lin); } while (0)

  int ak0 = ((0 + quad) ^ x7) * 8;
  int ak1 = ((4 + quad) ^ x7) * 8;

  s8v bfr[4];
#define PHASE(ABUF, BBUF, AKK, IP, LOADB, WAITN, ...) do { \
    if (LOADB) { \
      bfr[0] = *(const s8v*)((BBUF) + (wn +  0 + l16) * 64 + (AKK)); \
      bfr[1] = *(const s8v*)((BBUF) + (wn + 16 + l16) * 64 + (AKK)); \
      bfr[2] = *(const s8v*)((BBUF) + (wn + 32 + l16) * 64 + (AKK)); \
      bfr[3] = *(const s8v*)((BBUF) + (wn + 48 + l16) * 64 + (AKK)); \
    } \
    s8v af0 = *(const s8v*)((ABUF) + (wm + (IP) * 32 + l16) * 64 + (AKK)); \
    s8v af1 = *(const s8v*)((ABUF) + (wm + (IP) * 32 + 16 + l16) * 64 + (AKK)); \
    __VA_ARGS__; \
    { int wv_ = (WAITN); \
      if (wv_ == 6) asm volatile("s_waitcnt vmcnt(6)" ::: "memory"); \
      else if (wv_ == 0) asm volatile("s_waitcnt vmcnt(0)" ::: "memory"); } \
    asm volatile("" ::: "memory"); __builtin_amdgcn_s_barrier(); asm volatile("" ::: "memory"); \
    __builtin_amdgcn_s_setprio(1); \
    _Pragma("unroll") \
    for (int j = 0; j < 4; j++) { \
      acc[(IP)*2][j]   = __builtin_amdgcn_mfma_f32_16x16x32_bf16(af0, bfr[j], acc[(IP)*2][j],   0, 0, 0); \
      acc[(IP)*2+1][j] = __builtin_amdgcn_mfma_f32_16x16x32_bf16(af1, bfr[j], acc[(IP)*2+1][j], 0, 0, 0); \
    } \
    __builtin_amdgcn_s_setprio(0); \
    asm volatile("" ::: "memory"); __builtin_amdgcn_s_barrier(); asm volatile("" ::: "memory"); \
  } while (0)

  u16 *A0 = Ash, *A1 = Ash + 8192, *A2 = Ash + 16384;
  u16 *B0 = Bsh, *B1 = Bsh + 16384, *B2 = Bsh + 32768;

  SA(0, A0); SB0(0, B0); SB1(0, B0);
  SA(1, A1); SB0(1, B1); SB1(1, B1);
  asm volatile("s_waitcnt vmcnt(6)" ::: "memory");
  __builtin_amdgcn_s_barrier();
  asm volatile("" ::: "memory");

  int nkt = K >> 6;
  for (int t2 = 0; t2 < nkt; t2 += 2) {
    bool more = (t2 + 2 < nkt);
    PHASE(A0, B0, ak0, 0, true,  -1, if (more) SA(t2 + 2, A2));
    PHASE(A0, B0, ak0, 1, false, -1, if (more) SB0(t2 + 2, B2));
    PHASE(A0, B0, ak1, 0, true,  -1, if (more) SB1(t2 + 2, B2));
    PHASE(A0, B0, ak1, 1, false, (more ? 6 : 0), );
    PHASE(A1, B1, ak0, 0, true,  -1, if (more) SA(t2 + 3, A0));
    PHASE(A1, B1, ak0, 1, false, -1, if (more) SB0(t2 + 3, B0));
    PHASE(A1, B1, ak1, 0, true,  -1, if (more) SB1(t2 + 3, B0));
    PHASE(A1, B1, ak1, 1, false, (more ? 6 : -1), );
    u16* tA = A0; A0 = A2; A2 = A1; A1 = tA;
    u16* tB = B0; B0 = B2; B2 = B1; B1 = tB;
  }
#undef PHASE
#undef SA
#undef SB0
#undef SB1

  #pragma unroll
  for (int i = 0; i < 4; i++) {
    int rbase = mb + wm + i * 16 + quad * 4;
    #pragma unroll
    for (int j = 0; j < 4; j++) {
      int col = nb + wn + j * 16 + l16;
      if (MODE == 0) {
        u16* Cb = (u16*)C0;
        #pragma unroll
        for (int r = 0; r < 4; r++) Cb[(size_t)(rbase + r) * N + col] = f2bf(acc[i][j][r] * oscale);
      } else if (MODE == 1) {
        float* Cf = (float*)C0;
        #pragma unroll
        for (int r = 0; r < 4; r++) Cf[(size_t)(rbase + r) * N + col] = acc[i][j][r] + bias[col];
      } else {
        if (col < 512) {                  // K projection -> Kb [b*NC+t][512]
          u16* Kb = (u16*)C0;
          #pragma unroll
          for (int r = 0; r < 4; r++) Kb[(size_t)(rbase + r) * 512 + col] = f2bf(acc[i][j][r]);
        } else {                          // V projection -> Vt, transposed + key-permuted
          u16* Vt = (u16*)C1;
          int hd = col - 512, h = hd >> 6, d = hd & 63;
          int bb = rbase >> 10, tl = rbase & 1023;
          int tbase = tl & ~63, a0 = tl & 63;
          int pb = (a0 & 32) + ((a0 & 15) >> 2) * 8 + (((a0 >> 4) & 1) << 2);
          uint2 ov;
          ov.x = pack2(acc[i][j][0], acc[i][j][1]);
          ov.y = pack2(acc[i][j][2], acc[i][j][3]);
          *(uint2*)(Vt + ((size_t)(bb * NH + h) * DH + d) * NC + tbase + pb) = ov;
        }
      }
    }
  }
}

// ---------------- fused QKV projection (bf16 A from prep), XCD-chunked, KV first ----------------
__global__ __launch_bounds__(512, 2) void proj_all(const u16* __restrict__ xb, const u16* __restrict__ cb,
                                                   const u16* __restrict__ wqT, const u16* __restrict__ wkvT,
                                                   u16* __restrict__ Qb, u16* __restrict__ Kb,
                                                   u16* __restrict__ Vtb, float qscale) {
  __shared__ alignas(16) u16 Ash[3 * 8192];    // 48 KB
  __shared__ alignas(16) u16 Bsh[3 * 16384];   // 96 KB
  int bx = blockIdx.x;
  if (bx < 128) {  // KV: M=4096, N=1024, K=768 -> 32x4 blocks of 128x256
    int bi = (bx & 7) * 16 + (bx >> 3);        // XCD-chunked [0,128)
    gemm8p<2>(cb, wkvT, Kb, Vtb, nullptr, 1024, 768, 1.0f, bi & 3, bi >> 2, Ash, Bsh);
  } else {         // Q: M=16384, N=512, K=512 -> 128x2 blocks
    int bq = bx - 128;
    int bi = (bq & 7) * 32 + (bq >> 3);        // [0,256)
    gemm8p<0>(xb, wqT, Qb, nullptr, nullptr, 512, 512, qscale, bi & 1, bi >> 1, Ash, Bsh);
  }
}

// ---------------- output projection (fp32 out + bias) ----------------
__global__ __launch_bounds__(512, 2) void outproj(const u16* __restrict__ Ob, const u16* __restrict__ woT,
                                                  float* __restrict__ out, const float* __restrict__ bo) {
  __shared__ alignas(16) u16 Ash[3 * 8192];
  __shared__ alignas(16) u16 Bsh[3 * 16384];
  int bx = blockIdx.x;
  int bi = (bx & 7) * 32 + (bx >> 3);          // [0,256)
  gemm8p<1>(Ob, woT, out, nullptr, bo, 512, 512, 1.0f, bi & 1, bi >> 1, Ash, Bsh);
}

// ---------------- flash cross-attention: 64 q/wave, T15 2-deep kt pipeline ----------------
// R11: attn pinned at ~44us across R7-R10 (occupancy, traffic, reorder all null; every pipe
// <40%) -> within-wave in-order serialization of QK->SM->PV. Fix = T15 att[2]: carry pf
// across kt; per iteration compute QK(kt) and interleave PV(kt-1) (independent MFMAs)
// with SM(kt) slices, so the wave issues matrix work between exp2 clusters.
// V triple-buffered (stage kt+1 overwrites V(kt-2), dead since iter kt-1); K double-buffered;
// one __syncthreads per kt preserves all WAR edges. kt-loop unrolled x2 (pfA/pfB static).
__global__ __launch_bounds__(256, 2) void attn(const u16* __restrict__ Q, const u16* __restrict__ Kb,
                                               const u16* __restrict__ Vt, u16* __restrict__ O) {
  __shared__ alignas(16) u16 Kl[2][64][64];   // 16 KB
  __shared__ alignas(16) u16 Vl[3][64][64];   // 24 KB
  int bx = blockIdx.x;
  int bi = (bx & 7) * 64 + (bx >> 3);         // bijective XCD chunking (512 % 8 == 0)
  int qt = bi & 15, h = (bi >> 4) & 7, b = bi >> 7;
  int tid = threadIdx.x, wave = tid >> 6, lane = tid & 63, quad = lane >> 4, l16 = lane & 15;
  int q0 = qt * 256 + wave * 64;
  int x7 = l16 & 7;
  int cv0 = (quad ^ x7) * 8, cv1 = ((4 + quad) ^ x7) * 8;   // V read chunks (c0 / c1)

  int kr = tid >> 3, kc = (tid & 7) ^ (kr & 7);
  const u16* kg = Kb + ((size_t)b * NC + kr) * 512 + h * DH + kc * 8;
  const u16* vg = Vt + ((size_t)(b * NH + h) * DH + kr) * NC + kc * 8;

#define SK(kt, dst) do { const u16* s_ = kg + (size_t)(kt) * 64 * 512; \
    g2l16(s_, (dst) + tid * 8); g2l16(s_ + 32 * 512, (dst) + (tid + 256) * 8); } while (0)
#define SV(kt, dst) do { const u16* s_ = vg + (kt) * 64; \
    g2l16(s_, (dst) + tid * 8); g2l16(s_ + 32 * NC, (dst) + (tid + 256) * 8); } while (0)

  // Q B-frags for 4 n-subtiles x 2 dh-chunks, in regs for the whole kernel (32 VGPR)
  s8v aq[4][2];
  {
    const u16* Qp = Q + ((size_t)b * NQ + q0 + l16) * DI + h * DH + quad * 8;
    #pragma unroll
    for (int n = 0; n < 4; n++) {
      aq[n][0] = *(const s8v*)(Qp + (size_t)n * 16 * DI);
      aq[n][1] = *(const s8v*)(Qp + (size_t)n * 16 * DI + 32);
    }
  }
  s8v vones;
  #pragma unroll
  for (int i = 0; i < 8; i++) vones[i] = (short)0x3F80;

  f4v oacc[4][4];
  f4v lacc[4];
  #pragma unroll
  for (int d = 0; d < 4; d++)
    #pragma unroll
    for (int n = 0; n < 4; n++) oacc[d][n] = (f4v){0.f, 0.f, 0.f, 0.f};
  #pragma unroll
  for (int n = 0; n < 4; n++) lacc[n] = (f4v){0.f, 0.f, 0.f, 0.f};

  u16 *kc_ = (u16*)Kl[0], *ks_ = (u16*)Kl[1];
  u16 *vr_ = (u16*)Vl[0], *vc_ = (u16*)Vl[1], *vs_ = (u16*)Vl[2];

  // QK chunk: S[mi][n] over 16 keys starting at roff (16 MFMA), K from kc_
#define QKC(Sa, roff) do { \
    _Pragma("unroll") for (int mi = 0; mi < 2; mi++) \
      _Pragma("unroll") for (int n = 0; n < 4; n++) Sa[mi][n] = (f4v){0.f,0.f,0.f,0.f}; \
    __builtin_amdgcn_s_setprio(1); \
    _Pragma("unroll") for (int cd = 0; cd < 2; cd++) { \
      int ch = ((4 * cd + quad) ^ x7) * 8; \
      s8v ka_ = *(const s8v*)(kc_ + ((roff) + l16) * 64 + ch); \
      s8v kb_ = *(const s8v*)(kc_ + ((roff) + 16 + l16) * 64 + ch); \
      _Pragma("unroll") for (int n = 0; n < 4; n++) { \
        Sa[0][n] = __builtin_amdgcn_mfma_f32_16x16x32_bf16(ka_, aq[n][cd], Sa[0][n], 0, 0, 0); \
        Sa[1][n] = __builtin_amdgcn_mfma_f32_16x16x32_bf16(kb_, aq[n][cd], Sa[1][n], 0, 0, 0); } } \
    __builtin_amdgcn_s_setprio(0); } while (0)

  // one softmax slice: S[.][g] (8 vals) -> pfN[g]
#define SM_SLICE(Sa, pfN, g) do { \
    float p00 = EXP2(Sa[0][g][0]), p01 = EXP2(Sa[0][g][1]), p02 = EXP2(Sa[0][g][2]), p03 = EXP2(Sa[0][g][3]); \
    float p10 = EXP2(Sa[1][g][0]), p11 = EXP2(Sa[1][g][1]), p12 = EXP2(Sa[1][g][2]), p13 = EXP2(Sa[1][g][3]); \
    union { u32 d[4]; s8v v; } u_; \
    u_.d[0] = cvtpk(p00, p01); u_.d[1] = cvtpk(p02, p03); \
    u_.d[2] = cvtpk(p10, p11); u_.d[3] = cvtpk(p12, p13); \
    pfN[g] = u_.v; } while (0)

  // PV for one d-block using carried pfO (8 MFMA), V from vr_
#define PV_D(d, PFO0, PFO1) do { \
    __builtin_amdgcn_s_setprio(1); \
    s8v vf0_ = *(const s8v*)(vr_ + ((d) * 16 + l16) * 64 + cv0); \
    s8v vf1_ = *(const s8v*)(vr_ + ((d) * 16 + l16) * 64 + cv1); \
    _Pragma("unroll") for (int n = 0; n < 4; n++) \
      oacc[d][n] = __builtin_amdgcn_mfma_f32_16x16x32_bf16(vf0_, PFO0[n], oacc[d][n], 0, 0, 0); \
    _Pragma("unroll") for (int n = 0; n < 4; n++) \
      oacc[d][n] = __builtin_amdgcn_mfma_f32_16x16x32_bf16(vf1_, PFO1[n], oacc[d][n], 0, 0, 0); \
    __builtin_amdgcn_s_setprio(0); } while (0)

#define LACC(PFO0, PFO1) do { \
    __builtin_amdgcn_s_setprio(1); \
    _Pragma("unroll") for (int n = 0; n < 4; n++) \
      lacc[n] = __builtin_amdgcn_mfma_f32_16x16x32_bf16(vones, PFO0[n], lacc[n], 0, 0, 0); \
    _Pragma("unroll") for (int n = 0; n < 4; n++) \
      lacc[n] = __builtin_amdgcn_mfma_f32_16x16x32_bf16(vones, PFO1[n], lacc[n], 0, 0, 0); \
    __builtin_amdgcn_s_setprio(0); } while (0)

  // BODY(kt): barrier; stage kt+1; QK0(kt); PV(0,1)|SM0; QK1(kt); PV(2,3)|SM1; lacc; rotate.
#define BODY(PFO0, PFO1, PFN0, PFN1, KT) do { \
    __syncthreads(); \
    if ((KT) + 1 < 16) { SK((KT) + 1, ks_); SV((KT) + 1, vs_); } \
    f4v S0_[2][4], S1_[2][4]; \
    QKC(S0_, 0); \
    PV_D(0, PFO0, PFO1); SM_SLICE(S0_, PFN0, 0); SM_SLICE(S0_, PFN0, 1); \
    PV_D(1, PFO0, PFO1); SM_SLICE(S0_, PFN0, 2); SM_SLICE(S0_, PFN0, 3); \
    QKC(S1_, 32); \
    PV_D(2, PFO0, PFO1); SM_SLICE(S1_, PFN1, 0); SM_SLICE(S1_, PFN1, 1); \
    PV_D(3, PFO0, PFO1); SM_SLICE(S1_, PFN1, 2); SM_SLICE(S1_, PFN1, 3); \
    LACC(PFO0, PFO1); \
    { u16* t_ = kc_; kc_ = ks_; ks_ = t_; \
      u16* r_ = vr_; vr_ = vc_; vc_ = vs_; vs_ = r_; } } while (0)

  s8v pfA0[4], pfA1[4], pfB0[4], pfB1[4];

  // prologue: stage tiles 0,1; QK(0)+SM(0) -> pfA (no PV yet)
  SK(0, kc_); SV(0, vr_);
  SK(1, ks_); SV(1, vc_);
  __syncthreads();
  {
    f4v S0_[2][4], S1_[2][4];
    QKC(S0_, 0); QKC(S1_, 32);
    SM_SLICE(S0_, pfA0, 0); SM_SLICE(S0_, pfA0, 1); SM_SLICE(S0_, pfA0, 2); SM_SLICE(S0_, pfA0, 3);
    SM_SLICE(S1_, pfA1, 0); SM_SLICE(S1_, pfA1, 1); SM_SLICE(S1_, pfA1, 2); SM_SLICE(S1_, pfA1, 3);
  }
  { u16* t_ = kc_; kc_ = ks_; ks_ = t_; }   // kc_=K(1), ks_=K(0) free; vr_=V(0), vc_=V(1), vs_ free

  for (int kt = 1; kt < 16; kt += 2) {
    BODY(pfA0, pfA1, pfB0, pfB1, kt);
    if (kt + 1 < 16) BODY(pfB0, pfB1, pfA0, pfA1, kt + 1);
  }
  // epilogue: PV for tile 15 (pfB, V(15) now in vr_)
  PV_D(0, pfB0, pfB1); PV_D(1, pfB0, pfB1); PV_D(2, pfB0, pfB1); PV_D(3, pfB0, pfB1);
  LACC(pfB0, pfB1);
#undef BODY
#undef LACC
#undef PV_D
#undef SM_SLICE
#undef QKC
#undef SK
#undef SV

  float inv[4];
  #pragma unroll
  for (int n = 0; n < 4; n++) inv[n] = 1.0f / lacc[n][0];

  #pragma unroll
  for (int d = 0; d < 4; d++)
    #pragma unroll
    for (int n = 0; n < 4; n++) {
      int q = q0 + n * 16 + l16;
      uint2 ov;
      ov.x = cvtpk(oacc[d][n][0] * inv[n], oacc[d][n][1] * inv[n]);
      ov.y = cvtpk(oacc[d][n][2] * inv[n], oacc[d][n][3] * inv[n]);
      *(uint2*)(O + ((size_t)b * NQ + q) * DI + h * DH + d * 16 + quad * 4) = ov;
    }
}

extern "C" void kernel_launch(void* const* d_in, const int* in_sizes, int n_in,
                              void* d_out, int out_size, void* d_ws, size_t ws_size,
                              hipStream_t stream) {
  const float* x   = (const float*)d_in[0];
  const float* ctx = (const float*)d_in[1];
  const float* Wq  = (const float*)d_in[2];
  const float* Wk  = (const float*)d_in[3];
  const float* Wv  = (const float*)d_in[4];
  const float* Wo  = (const float*)d_in[5];
  const float* bo  = (const float*)d_in[6];
  float* out = (float*)d_out;

  u16* w    = (u16*)d_ws;                // workspace layout (bf16 elems)
  u16* xb   = w;                         // 8388608
  u16* cb   = xb   + 8388608;            // 3145728
  u16* wqT  = cb   + 3145728;            // 262144
  u16* wkvT = wqT  + 262144;             // 786432 (Wk^T rows 0-511, Wv^T rows 512-1023)
  u16* woT  = wkvT + 786432;             // 262144
  u16* Qb   = woT  + 262144;             // 8388608 (pre-scaled by 0.125*log2e)
  u16* Kbuf = Qb   + 8388608;            // 2097152 ([b*1024+t][512])
  u16* Vtb  = Kbuf + 2097152;            // 2097152 (key-permuted V^T)
  u16* Ob   = Vtb  + 2097152;            // 8388608

  const float qscale = 0.125f * 1.44269504f;  // softmax scale + log2(e) folded into Q

  prep<<<11648, 256, 0, stream>>>(x, ctx, Wq, Wk, Wv, Wo, xb, cb, wqT, wkvT, woT);
  proj_all<<<384, 512, 0, stream>>>(xb, cb, wqT, wkvT, Qb, Kbuf, Vtb, qscale);
  attn<<<512, 256, 0, stream>>>(Qb, Kbuf, Vtb, Ob);
  outproj<<<256, 512, 0, stream>>>(Ob, woT, out, bo);
}